// Round 4
// baseline (293.159 us; speedup 1.0000x reference)
//
#include <hip/hip_runtime.h>
#include <stdint.h>

typedef __attribute__((ext_vector_type(8))) short bf16x8;   // 8 bf16 = 4 VGPR (MFMA A/B frag)
typedef __attribute__((ext_vector_type(4))) float f32x4;    // MFMA C/D frag
typedef __attribute__((ext_vector_type(4))) unsigned short us4;
typedef __attribute__((ext_vector_type(8))) unsigned short us8;

__device__ __forceinline__ unsigned short f2bf(float f) {   // RNE f32 -> bf16
  union { float f; unsigned u; } x; x.f = f;
  unsigned r = x.u + 0x7FFFu + ((x.u >> 16) & 1u);
  return (unsigned short)(r >> 16);
}
__device__ __forceinline__ float bf2f(unsigned short h) {
  union { unsigned u; float f; } x; x.u = ((unsigned)h) << 16;
  return x.f;
}

// async global->LDS, 16B per lane; LDS dest is wave-uniform base + lane*16
#define GL2LDS(g, l) __builtin_amdgcn_global_load_lds( \
    (const __attribute__((address_space(1))) unsigned int*)(g), \
    (__attribute__((address_space(3))) unsigned int*)(l), 16, 0, 0)

// raw barrier with compiler memory fence (no vmcnt/lgkm drain at runtime)
#define BARRIER() do { asm volatile("" ::: "memory"); \
  __builtin_amdgcn_s_barrier(); asm volatile("" ::: "memory"); } while (0)
#define SCHED0() __builtin_amdgcn_sched_barrier(0)

// ---------------- fused prep (unchanged) ----------------
__global__ __launch_bounds__(256)
void prep(const float* __restrict__ x,
          const float* __restrict__ wq, const float* __restrict__ wk,
          const float* __restrict__ wv, const float* __restrict__ wo,
          unsigned short* __restrict__ xb,
          unsigned short* __restrict__ wqb, unsigned short* __restrict__ wkb,
          unsigned short* __restrict__ vtb, unsigned short* __restrict__ opT)
{
  __shared__ float t[32][33];
  const int b = blockIdx.x;
  if (b < 10240) {
    const float* in; unsigned short* out; int i;
    if (b < 8192)      { in = x;  out = xb;  i = b * 256 + threadIdx.x; }
    else if (b < 9216) { in = wq; out = wqb; i = (b - 8192) * 256 + threadIdx.x; }
    else               { in = wk; out = wkb; i = (b - 9216) * 256 + threadIdx.x; }
    const float4 f = ((const float4*)in)[i];
    us4 v;
    v[0] = f2bf(f.x); v[1] = f2bf(f.y); v[2] = f2bf(f.z); v[3] = f2bf(f.w);
    ((us4*)out)[i] = v;
  } else {
    const float* in = (b < 11264) ? wv : wo;
    unsigned short* out = (b < 11264) ? vtb : opT;
    const int tb = (b < 11264) ? (b - 10240) : (b - 11264);
    const int bx = (tb & 31) * 32, by = (tb >> 5) * 32;
    const int tx = threadIdx.x & 31, ty = threadIdx.x >> 5;
#pragma unroll
    for (int i = 0; i < 32; i += 8)
      t[ty + i][tx] = in[(size_t)(by + ty + i) * 1024 + bx + tx];
    __syncthreads();
#pragma unroll
    for (int i = 0; i < 32; i += 8)
      out[(size_t)(bx + ty + i) * 1024 + by + tx] = f2bf(t[tx][ty + i]);
  }
}

// ======== m201-faithful 256x256 8-phase K-loop (BK=64, 512 thr / 8 waves) ====
// 2 K-tiles unrolled per iteration, STATIC LDS offsets (2 bufs x 64 KiB):
//   buf b @ b*65536: Ah0 @+0, Ah1 @+16K, Bh0 @+32K, Bh1 @+48K ([128][64] bf16 each)
// Wave grid 2M x 4N; quadrant (mh,nh): rows mh*128+wm*64+fi*16, cols
// nh*128+wn*32+fj*16 (each quadrant touches exactly one A-half / B-half).
// Quadrant order (0,0),(0,1),(1,1),(1,0): Ah0 free after phi2, Bh1 after phi3,
// Ah1/Bh0 after phi4 -> per-iter stage ledger (tiles t=buf0, t+1=buf1):
//   p1:Ah1(t+1) p2:Bh0(t+1) p3:Ah0(t+2) p4:Bh1(t+2)+vmcnt(4)
//   p5:Ah1(t+2) p6:Bh0(t+2) p7:Ah0(t+3) p8:Bh1(t+3)+vmcnt(4)
// Gate check: vmcnt(4) at p4 retires through p2 => tile t+1 fully landed
// before p5; at p8 retires through p6 => tile t+2 landed before next p1.
// XOR swizzle byte^=((l16&7)<<4) via inverse-swizzled global source + same
// XOR on ds_read address. Frag reuse: afr (re-read p3/p5/p7), b0 (p1->p4),
// b1 (p2->p3). Pure 16-MFMA clusters under setprio, fenced by sched_barrier.
__device__ __forceinline__ void kloop8p(
    const unsigned short* __restrict__ Ag, const unsigned short* __restrict__ Bg,
    const int lda, const int ldw, const int NT,   // NT = K/64, even, >= 4
    char* smem, f32x4 (&acc)[8][4])
{
  const int tid = threadIdx.x;
  const int lane = tid & 63, wave = tid >> 6;
  const int quad = lane >> 4, l16 = lane & 15;
  const int wm = wave >> 2, wn = wave & 3;

  const int c0 = (quad * 16) ^ ((l16 & 7) << 4);   // swizzled ks=0 byte col
  const int aR = (wm * 64 + l16) * 128;            // byte row base in A-half
  const int bR = (wn * 32 + l16) * 128;            // byte row base in B-half

  // stage-side: thread covers LDS rows (tid>>3), (tid>>3)+64 of a half
  const int scol = ((tid & 7) ^ ((tid >> 3) & 7)) << 3;   // inv-swizzled elem col
  const unsigned short* As = Ag + (size_t)(tid >> 3) * lda + scol;
  const unsigned short* Bs = Bg + (size_t)(tid >> 3) * ldw + scol;

#define SA(buf, mh, kt) do { \
    GL2LDS(As + (size_t)((mh) * 128) * lda + (kt) * 64,      smem + (buf) * 65536 + (mh) * 16384 +        tid * 16); \
    GL2LDS(As + (size_t)((mh) * 128 + 64) * lda + (kt) * 64, smem + (buf) * 65536 + (mh) * 16384 + 8192 + tid * 16); } while (0)
#define SB(buf, nh, kt) do { \
    GL2LDS(Bs + (size_t)((nh) * 128) * ldw + (kt) * 64,      smem + (buf) * 65536 + 32768 + (nh) * 16384 +        tid * 16); \
    GL2LDS(Bs + (size_t)((nh) * 128 + 64) * ldw + (kt) * 64, smem + (buf) * 65536 + 32768 + (nh) * 16384 + 8192 + tid * 16); } while (0)
#define RA(buf, mh) do { _Pragma("unroll") for (int fi = 0; fi < 4; ++fi) { \
    afr[fi][0] = *(const bf16x8*)(smem + (buf) * 65536 + (mh) * 16384 + aR + fi * 2048 + c0); \
    afr[fi][1] = *(const bf16x8*)(smem + (buf) * 65536 + (mh) * 16384 + aR + fi * 2048 + (c0 ^ 64)); } } while (0)
#define RB(buf, nh, bb) do { _Pragma("unroll") for (int fj = 0; fj < 2; ++fj) { \
    bb[fj][0] = *(const bf16x8*)(smem + (buf) * 65536 + 32768 + (nh) * 16384 + bR + fj * 2048 + c0); \
    bb[fj][1] = *(const bf16x8*)(smem + (buf) * 65536 + 32768 + (nh) * 16384 + bR + fj * 2048 + (c0 ^ 64)); } } while (0)
#define MM(mh, nh, bb) do { __builtin_amdgcn_s_setprio(1); \
    _Pragma("unroll") for (int fi = 0; fi < 4; ++fi) \
    _Pragma("unroll") for (int fj = 0; fj < 2; ++fj) \
    _Pragma("unroll") for (int ks = 0; ks < 2; ++ks) \
      acc[(mh) * 4 + fi][(nh) * 2 + fj] = __builtin_amdgcn_mfma_f32_16x16x32_bf16( \
          afr[fi][ks], bb[fj][ks], acc[(mh) * 4 + fi][(nh) * 2 + fj], 0, 0, 0); \
    __builtin_amdgcn_s_setprio(0); } while (0)

  bf16x8 afr[4][2], b0[2][2], b1[2][2];

  // prologue: tile0 full (8 loads) + tile1 {Ah0, Bh1} (4 loads)
  SA(0, 0, 0); SA(0, 1, 0); SB(0, 0, 0); SB(0, 1, 0);
  SA(1, 0, 1); SB(1, 1, 1);
  asm volatile("s_waitcnt vmcnt(4)" ::: "memory");
  __builtin_amdgcn_s_barrier();

  for (int t = 0; t < NT; t += 2) {
    const bool s2 = (t + 2 < NT), s3 = (t + 3 < NT);

    // ---- p1: tile t, quadrant (0,0)
    RA(0, 0); RB(0, 0, b0);
    SA(1, 1, t + 1);
    BARRIER(); SCHED0(); MM(0, 0, b0); SCHED0(); BARRIER();
    // ---- p2: (0,1)
    RB(0, 1, b1);
    SB(1, 0, t + 1);
    BARRIER(); SCHED0(); MM(0, 1, b1); SCHED0(); BARRIER();
    // ---- p3: (1,1)
    RA(0, 1);
    if (s2) SA(0, 0, t + 2);
    BARRIER(); SCHED0(); MM(1, 1, b1); SCHED0(); BARRIER();
    // ---- p4: (1,0) + gate
    if (s2) SB(0, 1, t + 2);
    BARRIER(); SCHED0(); MM(1, 0, b0);
    if (s2) { asm volatile("s_waitcnt vmcnt(4)" ::: "memory"); }
    else    { asm volatile("s_waitcnt vmcnt(0)" ::: "memory"); }
    SCHED0(); BARRIER();

    // ---- p5: tile t+1, quadrant (0,0)
    RA(1, 0); RB(1, 0, b0);
    if (s2) SA(0, 1, t + 2);
    BARRIER(); SCHED0(); MM(0, 0, b0); SCHED0(); BARRIER();
    // ---- p6: (0,1)
    RB(1, 1, b1);
    if (s2) SB(0, 0, t + 2);
    BARRIER(); SCHED0(); MM(0, 1, b1); SCHED0(); BARRIER();
    // ---- p7: (1,1)
    RA(1, 1);
    if (s3) SA(1, 0, t + 3);
    BARRIER(); SCHED0(); MM(1, 1, b1); SCHED0(); BARRIER();
    // ---- p8: (1,0) + gate
    if (s3) SB(1, 1, t + 3);
    BARRIER(); SCHED0(); MM(1, 0, b0);
    if (s3) { asm volatile("s_waitcnt vmcnt(4)" ::: "memory"); }
    else    { asm volatile("s_waitcnt vmcnt(0)" ::: "memory"); }
    SCHED0(); BARRIER();
  }
#undef SA
#undef SB
#undef RA
#undef RB
#undef MM
}

// ---------------- epilogues (2M x 4N 256^2 layout) ----------------
// row = m0 + (mf>>2)*128 + wm*64 + (mf&3)*16 + quad*4 + r
// col = n0 + (an>>1)*128 + wn*32 + (an&1)*16 + l16
__device__ __forceinline__ void epi_bf16(const f32x4 (&acc)[8][4], unsigned short* __restrict__ C,
                                         int ldc, int m0, int n0, char* smem)
{
  const int tid = threadIdx.x, lane = tid & 63, wave = tid >> 6;
  const int quad = lane >> 4, l16 = lane & 15;
  const int wm = wave >> 2, wn = wave & 3;
  unsigned short* patch = (unsigned short*)smem + wave * (16 * 72);
#pragma unroll
  for (int mf = 0; mf < 8; ++mf) {
#pragma unroll
    for (int an = 0; an < 4; ++an)
#pragma unroll
      for (int r = 0; r < 4; ++r)
        patch[(quad * 4 + r) * 72 + an * 16 + l16] = f2bf(acc[mf][an][r]);
    __builtin_amdgcn_wave_barrier();
    const int grow0 = m0 + (mf >> 2) * 128 + wm * 64 + (mf & 3) * 16;
#pragma unroll
    for (int it = 0; it < 2; ++it) {
      const int rr = it * 8 + (lane >> 3);
      const int cp = (lane & 7) * 8;
      us8 v = *(const us8*)&patch[rr * 72 + cp];
      const int gcol = n0 + (cp >> 5) * 128 + wn * 32 + (cp & 31);
      *(us8*)&C[(size_t)(grow0 + rr) * ldc + gcol] = v;
    }
    __builtin_amdgcn_wave_barrier();
  }
}

__device__ __forceinline__ void epi_f32(const f32x4 (&acc)[8][4], float* __restrict__ C,
                                        int ldc, int m0, int n0, char* smem)
{
  const int tid = threadIdx.x, lane = tid & 63, wave = tid >> 6;
  const int quad = lane >> 4, l16 = lane & 15;
  const int wm = wave >> 2, wn = wave & 3;
  float* patch = (float*)smem + wave * (16 * 68);
#pragma unroll
  for (int mf = 0; mf < 8; ++mf) {
#pragma unroll
    for (int an = 0; an < 4; ++an)
#pragma unroll
      for (int r = 0; r < 4; ++r)
        patch[(quad * 4 + r) * 68 + an * 16 + l16] = acc[mf][an][r];
    __builtin_amdgcn_wave_barrier();
    const int grow0 = m0 + (mf >> 2) * 128 + wm * 64 + (mf & 3) * 16;
#pragma unroll
    for (int j = 0; j < 4; ++j) {
      const int rr = j * 4 + (lane >> 4);
      const int cp = (lane & 15) * 4;
      float4 v = *(const float4*)&patch[rr * 68 + cp];
      const int gcol = n0 + (cp >> 5) * 128 + wn * 32 + (cp & 31);
      *(float4*)&C[(size_t)(grow0 + rr) * ldc + gcol] = v;
    }
    __builtin_amdgcn_wave_barrier();
  }
}

// ---------------- fused QKV' projection (BM=BN=256) ----------------
// blockIdx.x in [0,12): wsel = x>>2, n0 = (x&3)*256.
// wsel 0: Q, 1: K, 2: V' = x @ Wct^T stored transposed VT[b][j][s].
__global__ __launch_bounds__(512, 2)
void gemm_qkv(const unsigned short* __restrict__ xb,
              const unsigned short* __restrict__ wq, const unsigned short* __restrict__ wk,
              const unsigned short* __restrict__ wct,
              unsigned short* __restrict__ Q, unsigned short* __restrict__ Kb,
              unsigned short* __restrict__ VT)
{
  const int m0 = blockIdx.y * 256;
  const int wsel = blockIdx.x >> 2;
  const int n0 = (blockIdx.x & 3) * 256;
  const unsigned short* W = (wsel == 0) ? wq : (wsel == 1) ? wk : wct;

  __shared__ __align__(16) char smem[131072];
  f32x4 acc[8][4] = {};
  kloop8p(xb + (size_t)m0 * 1024, W + (size_t)n0 * 1024, 1024, 1024, 16, smem, acc);
  __syncthreads();

  const int lane = threadIdx.x & 63, wave = threadIdx.x >> 6;
  const int quad = lane >> 4, l16 = lane & 15;
  const int wm = wave >> 2, wn = wave & 3;
  if (wsel == 2) {
#pragma unroll
    for (int mf = 0; mf < 8; ++mf) {
      const int gr = m0 + (mf >> 2) * 128 + wm * 64 + (mf & 3) * 16 + quad * 4;
      const int b = gr >> 11, s = gr & 2047;
#pragma unroll
      for (int an = 0; an < 4; ++an) {
        const int gc = n0 + (an >> 1) * 128 + wn * 32 + (an & 1) * 16 + l16;
        us4 v;
#pragma unroll
        for (int r = 0; r < 4; ++r) v[r] = f2bf(acc[mf][an][r]);
        *(us4*)(VT + (size_t)b * (1024 * 2048) + (size_t)gc * 2048 + s) = v;
      }
    }
  } else {
    epi_bf16(acc, (wsel == 0) ? Q : Kb, 1024, m0, n0, smem);
  }
}

// ---------------- generic bf16 GEMM: C = A @ W^T (BM=BN=256) ----------------
// MODE 0: C bf16 store. MODE 1: C f32 store.
// CAUSAL: block skip (n0 > m0+255). PVLIM: Keff = m0+256.
template<int MODE, bool CAUSAL, bool PVLIM>
__global__ __launch_bounds__(512, 2)
void gemm_bt(const unsigned short* __restrict__ A, const unsigned short* __restrict__ W,
             void* __restrict__ Cv, int lda, int ldw, int ldc, int K,
             long long sAz, long long sWz, long long sCz)
{
  const int m0 = blockIdx.y * 256;
  const int n0 = blockIdx.x * 256;
  if (CAUSAL && n0 > m0 + 255) return;
  const int z = blockIdx.z;

  __shared__ __align__(16) char smem[131072];
  f32x4 acc[8][4] = {};
  const int Keff = PVLIM ? (m0 + 256) : K;
  kloop8p(A + (size_t)z * sAz + (size_t)m0 * lda,
          W + (size_t)z * sWz + (size_t)n0 * ldw,
          lda, ldw, Keff >> 6, smem, acc);
  __syncthreads();

  if (MODE == 0)
    epi_bf16(acc, (unsigned short*)Cv + (size_t)z * sCz, ldc, m0, n0, smem);
  else
    epi_f32(acc, (float*)Cv + (size_t)z * sCz, ldc, m0, n0, smem);
}

// causal softmax; blockIdx.x = b*2048 + r; valid cols [0,r]; scale 1/32 pre-exp.
// Zero-fills out to the 256-aligned band [0, ((r>>8)+1)*256) that BM=256 PV reads.
__global__ __launch_bounds__(256)
void softmax_causal(unsigned short* __restrict__ SP)
{
  const int gid = blockIdx.x;
  const int r   = gid & 2047;
  const int tid = threadIdx.x;
  unsigned short* row = SP + (size_t)gid * 2048;
  const int n  = r + 1;
  const int it = (r >> 8) + 1;   // active 256-col chunks

  float vals[8];
  float lmax = -1e30f;
#pragma unroll
  for (int i = 0; i < 8; ++i) {
    const int c = tid + i * 256;
    if (i < it) {
      const float f = bf2f(row[c]);
      vals[i] = f;
      if (c < n) lmax = fmaxf(lmax, f);
    }
  }
#pragma unroll
  for (int m = 32; m; m >>= 1) lmax = fmaxf(lmax, __shfl_xor(lmax, m, 64));
  __shared__ float redm[4], reds[4];
  if ((tid & 63) == 0) redm[tid >> 6] = lmax;
  __syncthreads();
  lmax = fmaxf(fmaxf(redm[0], redm[1]), fmaxf(redm[2], redm[3]));

  float e[8];
  float lsum = 0.f;
#pragma unroll
  for (int i = 0; i < 8; ++i) {
    const int c = tid + i * 256;
    const float ev = (c < n) ? __expf((vals[i] - lmax) * 0.03125f) : 0.f;
    e[i] = ev;
    lsum += ev;
  }
#pragma unroll
  for (int m = 32; m; m >>= 1) lsum += __shfl_xor(lsum, m, 64);
  if ((tid & 63) == 0) reds[tid >> 6] = lsum;
  __syncthreads();
  lsum = reds[0] + reds[1] + reds[2] + reds[3];
  const float inv = 1.f / lsum;
#pragma unroll
  for (int i = 0; i < 8; ++i) {
    const int c = tid + i * 256;
    if (i < it) row[c] = f2bf(e[i] * inv);
  }
}

extern "C" void kernel_launch(void* const* d_in, const int* in_sizes, int n_in,
                              void* d_out, int out_size, void* d_ws, size_t ws_size,
                              hipStream_t stream)
{
  (void)in_sizes; (void)n_in; (void)out_size; (void)ws_size;
  // dict order: k, q, v, out_proj, x — f32 inputs, f32 output
  const float* wk_f = (const float*)d_in[0];
  const float* wq_f = (const float*)d_in[1];
  const float* wv_f = (const float*)d_in[2];
  const float* wo_f = (const float*)d_in[3];
  const float* x_f  = (const float*)d_in[4];
  float* out = (float*)d_out;

  // ws layout (98 MiB):
  char* p = (char*)d_ws;
  unsigned short* xb   = (unsigned short*)(p);                       // [0,16M)
  unsigned short* Q    = (unsigned short*)(p + ((size_t)16 << 20));  // [16,32M)
  unsigned short* Kb   = (unsigned short*)(p + ((size_t)32 << 20));  // [32,48M)
  unsigned short* VT   = (unsigned short*)(p + ((size_t)48 << 20));  // [48,64M): V'^T [B][j][s]
  unsigned short* SP   = (unsigned short*)(p + ((size_t)64 << 20));  // [64,96M): [B][S][S]
  unsigned short* wqb  = (unsigned short*)(p + ((size_t)64 << 20));  // aliases (dead before scores)
  unsigned short* wkb  = (unsigned short*)(p + ((size_t)66 << 20));
  unsigned short* vtb  = (unsigned short*)(p + ((size_t)68 << 20));  // v^T bf16
  unsigned short* wctb = (unsigned short*)(p + ((size_t)70 << 20));  // Wct = (v^T@out_proj)^T
  unsigned short* opT  = (unsigned short*)(p + ((size_t)96 << 20));  // [96,98M)

  dim3 blk256(256), blk512(512);

  // conversions + transposes (x, wq, wk, v^T, out_proj^T)
  prep<<<dim3(12288), blk256, 0, stream>>>(x_f, wq_f, wk_f, wv_f, wo_f, xb, wqb, wkb, vtb, opT);

  // Wct[j][e] = sum_d out_proj[d][j] * v[d][e], tiny GEMM (1024^3)
  gemm_bt<0, false, false><<<dim3(4, 4, 1), blk512, 0, stream>>>(opT, vtb, wctb,
      1024, 1024, 1024, 1024, 0, 0, 0);

  // fused Q/K/V' projections: M=8192, N=3*1024, K=1024
  gemm_qkv<<<dim3(12, 32), blk512, 0, stream>>>(xb, wqb, wkb, wctb, Q, Kb, VT);

  // scores (all batches): [B][2048,2048] = Q @ K^T, causal block skip (144 live blocks)
  gemm_bt<0, true, false><<<dim3(8, 8, 4), blk512, 0, stream>>>(Q, Kb, SP,
      1024, 1024, 2048, 1024,
      (long long)2048 * 1024, (long long)2048 * 1024, (long long)2048 * 2048);

  // P = causal_softmax(scores/32), in place, all batches (256-aligned zero band)
  softmax_causal<<<dim3(8192), blk256, 0, stream>>>(SP);

  // out = P @ V', Keff = m0+256, f32 direct to d_out (128 blocks)
  gemm_bt<1, false, true><<<dim3(4, 8, 4), blk512, 0, stream>>>(SP, VT, out,
      2048, 2048, 1024, 2048,
      (long long)2048 * 2048, (long long)1024 * 2048, (long long)2048 * 1024);
}

// Round 5
// 276.620 us; speedup vs baseline: 1.0598x; 1.0598x over previous
//
#include <hip/hip_runtime.h>
#include <stdint.h>

typedef __attribute__((ext_vector_type(8))) short bf16x8;   // 8 bf16 = 4 VGPR (MFMA A/B frag)
typedef __attribute__((ext_vector_type(4))) float f32x4;    // MFMA C/D frag
typedef __attribute__((ext_vector_type(4))) unsigned short us4;
typedef __attribute__((ext_vector_type(8))) unsigned short us8;

__device__ __forceinline__ unsigned short f2bf(float f) {   // RNE f32 -> bf16
  union { float f; unsigned u; } x; x.f = f;
  unsigned r = x.u + 0x7FFFu + ((x.u >> 16) & 1u);
  return (unsigned short)(r >> 16);
}
__device__ __forceinline__ float bf2f(unsigned short h) {
  union { unsigned u; float f; } x; x.u = ((unsigned)h) << 16;
  return x.f;
}

// async global->LDS, 16B per lane; LDS dest is wave-uniform base + lane*16
#define GL2LDS(g, l) __builtin_amdgcn_global_load_lds( \
    (const __attribute__((address_space(1))) unsigned int*)(g), \
    (__attribute__((address_space(3))) unsigned int*)(l), 16, 0, 0)

// raw barrier with compiler memory fence (no vmcnt/lgkm drain at runtime)
#define BARRIER() do { asm volatile("" ::: "memory"); \
  __builtin_amdgcn_s_barrier(); asm volatile("" ::: "memory"); } while (0)
#define SCHED0() __builtin_amdgcn_sched_barrier(0)

// ---------------- fused prep (unchanged) ----------------
__global__ __launch_bounds__(256)
void prep(const float* __restrict__ x,
          const float* __restrict__ wq, const float* __restrict__ wk,
          const float* __restrict__ wv, const float* __restrict__ wo,
          unsigned short* __restrict__ xb,
          unsigned short* __restrict__ wqb, unsigned short* __restrict__ wkb,
          unsigned short* __restrict__ vtb, unsigned short* __restrict__ opT)
{
  __shared__ float t[32][33];
  const int b = blockIdx.x;
  if (b < 10240) {
    const float* in; unsigned short* out; int i;
    if (b < 8192)      { in = x;  out = xb;  i = b * 256 + threadIdx.x; }
    else if (b < 9216) { in = wq; out = wqb; i = (b - 8192) * 256 + threadIdx.x; }
    else               { in = wk; out = wkb; i = (b - 9216) * 256 + threadIdx.x; }
    const float4 f = ((const float4*)in)[i];
    us4 v;
    v[0] = f2bf(f.x); v[1] = f2bf(f.y); v[2] = f2bf(f.z); v[3] = f2bf(f.w);
    ((us4*)out)[i] = v;
  } else {
    const float* in = (b < 11264) ? wv : wo;
    unsigned short* out = (b < 11264) ? vtb : opT;
    const int tb = (b < 11264) ? (b - 10240) : (b - 11264);
    const int bx = (tb & 31) * 32, by = (tb >> 5) * 32;
    const int tx = threadIdx.x & 31, ty = threadIdx.x >> 5;
#pragma unroll
    for (int i = 0; i < 32; i += 8)
      t[ty + i][tx] = in[(size_t)(by + ty + i) * 1024 + bx + tx];
    __syncthreads();
#pragma unroll
    for (int i = 0; i < 32; i += 8)
      out[(size_t)(bx + ty + i) * 1024 + by + tx] = f2bf(t[tx][ty + i]);
  }
}

// ======== m201-faithful 256x256 8-phase K-loop (BK=64, 512 thr / 8 waves) ====
// (unchanged from round 4 — 973 TF in-block measured)
__device__ __forceinline__ void kloop8p(
    const unsigned short* __restrict__ Ag, const unsigned short* __restrict__ Bg,
    const int lda, const int ldw, const int NT,   // NT = K/64, even, >= 2
    char* smem, f32x4 (&acc)[8][4])
{
  const int tid = threadIdx.x;
  const int lane = tid & 63, wave = tid >> 6;
  const int quad = lane >> 4, l16 = lane & 15;
  const int wm = wave >> 2, wn = wave & 3;

  const int c0 = (quad * 16) ^ ((l16 & 7) << 4);   // swizzled ks=0 byte col
  const int aR = (wm * 64 + l16) * 128;            // byte row base in A-half
  const int bR = (wn * 32 + l16) * 128;            // byte row base in B-half

  const int scol = ((tid & 7) ^ ((tid >> 3) & 7)) << 3;   // inv-swizzled elem col
  const unsigned short* As = Ag + (size_t)(tid >> 3) * lda + scol;
  const unsigned short* Bs = Bg + (size_t)(tid >> 3) * ldw + scol;

#define SA(buf, mh, kt) do { \
    GL2LDS(As + (size_t)((mh) * 128) * lda + (kt) * 64,      smem + (buf) * 65536 + (mh) * 16384 +        tid * 16); \
    GL2LDS(As + (size_t)((mh) * 128 + 64) * lda + (kt) * 64, smem + (buf) * 65536 + (mh) * 16384 + 8192 + tid * 16); } while (0)
#define SB(buf, nh, kt) do { \
    GL2LDS(Bs + (size_t)((nh) * 128) * ldw + (kt) * 64,      smem + (buf) * 65536 + 32768 + (nh) * 16384 +        tid * 16); \
    GL2LDS(Bs + (size_t)((nh) * 128 + 64) * ldw + (kt) * 64, smem + (buf) * 65536 + 32768 + (nh) * 16384 + 8192 + tid * 16); } while (0)
#define RA(buf, mh) do { _Pragma("unroll") for (int fi = 0; fi < 4; ++fi) { \
    afr[fi][0] = *(const bf16x8*)(smem + (buf) * 65536 + (mh) * 16384 + aR + fi * 2048 + c0); \
    afr[fi][1] = *(const bf16x8*)(smem + (buf) * 65536 + (mh) * 16384 + aR + fi * 2048 + (c0 ^ 64)); } } while (0)
#define RB(buf, nh, bb) do { _Pragma("unroll") for (int fj = 0; fj < 2; ++fj) { \
    bb[fj][0] = *(const bf16x8*)(smem + (buf) * 65536 + 32768 + (nh) * 16384 + bR + fj * 2048 + c0); \
    bb[fj][1] = *(const bf16x8*)(smem + (buf) * 65536 + 32768 + (nh) * 16384 + bR + fj * 2048 + (c0 ^ 64)); } } while (0)
#define MM(mh, nh, bb) do { __builtin_amdgcn_s_setprio(1); \
    _Pragma("unroll") for (int fi = 0; fi < 4; ++fi) \
    _Pragma("unroll") for (int fj = 0; fj < 2; ++fj) \
    _Pragma("unroll") for (int ks = 0; ks < 2; ++ks) \
      acc[(mh) * 4 + fi][(nh) * 2 + fj] = __builtin_amdgcn_mfma_f32_16x16x32_bf16( \
          afr[fi][ks], bb[fj][ks], acc[(mh) * 4 + fi][(nh) * 2 + fj], 0, 0, 0); \
    __builtin_amdgcn_s_setprio(0); } while (0)

  bf16x8 afr[4][2], b0[2][2], b1[2][2];

  // prologue: tile0 full (8 loads) + tile1 {Ah0, Bh1} (4 loads)
  SA(0, 0, 0); SA(0, 1, 0); SB(0, 0, 0); SB(0, 1, 0);
  SA(1, 0, 1); SB(1, 1, 1);
  asm volatile("s_waitcnt vmcnt(4)" ::: "memory");
  __builtin_amdgcn_s_barrier();

  for (int t = 0; t < NT; t += 2) {
    const bool s2 = (t + 2 < NT), s3 = (t + 3 < NT);

    // ---- p1: tile t, quadrant (0,0)
    RA(0, 0); RB(0, 0, b0);
    SA(1, 1, t + 1);
    BARRIER(); SCHED0(); MM(0, 0, b0); SCHED0(); BARRIER();
    // ---- p2: (0,1)
    RB(0, 1, b1);
    SB(1, 0, t + 1);
    BARRIER(); SCHED0(); MM(0, 1, b1); SCHED0(); BARRIER();
    // ---- p3: (1,1)
    RA(0, 1);
    if (s2) SA(0, 0, t + 2);
    BARRIER(); SCHED0(); MM(1, 1, b1); SCHED0(); BARRIER();
    // ---- p4: (1,0) + gate
    if (s2) SB(0, 1, t + 2);
    BARRIER(); SCHED0(); MM(1, 0, b0);
    if (s2) { asm volatile("s_waitcnt vmcnt(4)" ::: "memory"); }
    else    { asm volatile("s_waitcnt vmcnt(0)" ::: "memory"); }
    SCHED0(); BARRIER();

    // ---- p5: tile t+1, quadrant (0,0)
    RA(1, 0); RB(1, 0, b0);
    if (s2) SA(0, 1, t + 2);
    BARRIER(); SCHED0(); MM(0, 0, b0); SCHED0(); BARRIER();
    // ---- p6: (0,1)
    RB(1, 1, b1);
    if (s2) SB(0, 0, t + 2);
    BARRIER(); SCHED0(); MM(0, 1, b1); SCHED0(); BARRIER();
    // ---- p7: (1,1)
    RA(1, 1);
    if (s3) SA(1, 0, t + 3);
    BARRIER(); SCHED0(); MM(1, 1, b1); SCHED0(); BARRIER();
    // ---- p8: (1,0) + gate
    if (s3) SB(1, 1, t + 3);
    BARRIER(); SCHED0(); MM(1, 0, b0);
    if (s3) { asm volatile("s_waitcnt vmcnt(4)" ::: "memory"); }
    else    { asm volatile("s_waitcnt vmcnt(0)" ::: "memory"); }
    SCHED0(); BARRIER();
  }
#undef SA
#undef SB
#undef RA
#undef RB
#undef MM
}

// ---------------- epilogues (2M x 4N 256^2 layout) ----------------
__device__ __forceinline__ void epi_bf16(const f32x4 (&acc)[8][4], unsigned short* __restrict__ C,
                                         int ldc, int m0, int n0, char* smem)
{
  const int tid = threadIdx.x, lane = tid & 63, wave = tid >> 6;
  const int quad = lane >> 4, l16 = lane & 15;
  const int wm = wave >> 2, wn = wave & 3;
  unsigned short* patch = (unsigned short*)smem + wave * (16 * 72);
#pragma unroll
  for (int mf = 0; mf < 8; ++mf) {
#pragma unroll
    for (int an = 0; an < 4; ++an)
#pragma unroll
      for (int r = 0; r < 4; ++r)
        patch[(quad * 4 + r) * 72 + an * 16 + l16] = f2bf(acc[mf][an][r]);
    __builtin_amdgcn_wave_barrier();
    const int grow0 = m0 + (mf >> 2) * 128 + wm * 64 + (mf & 3) * 16;
#pragma unroll
    for (int it = 0; it < 2; ++it) {
      const int rr = it * 8 + (lane >> 3);
      const int cp = (lane & 7) * 8;
      us8 v = *(const us8*)&patch[rr * 72 + cp];
      const int gcol = n0 + (cp >> 5) * 128 + wn * 32 + (cp & 31);
      *(us8*)&C[(size_t)(grow0 + rr) * ldc + gcol] = v;
    }
    __builtin_amdgcn_wave_barrier();
  }
}

__device__ __forceinline__ void epi_f32(const f32x4 (&acc)[8][4], float* __restrict__ C,
                                        int ldc, int m0, int n0, char* smem)
{
  const int tid = threadIdx.x, lane = tid & 63, wave = tid >> 6;
  const int quad = lane >> 4, l16 = lane & 15;
  const int wm = wave >> 2, wn = wave & 3;
  float* patch = (float*)smem + wave * (16 * 68);
#pragma unroll
  for (int mf = 0; mf < 8; ++mf) {
#pragma unroll
    for (int an = 0; an < 4; ++an)
#pragma unroll
      for (int r = 0; r < 4; ++r)
        patch[(quad * 4 + r) * 68 + an * 16 + l16] = acc[mf][an][r];
    __builtin_amdgcn_wave_barrier();
    const int grow0 = m0 + (mf >> 2) * 128 + wm * 64 + (mf & 3) * 16;
#pragma unroll
    for (int j = 0; j < 4; ++j) {
      const int rr = j * 4 + (lane >> 4);
      const int cp = (lane & 15) * 4;
      float4 v = *(const float4*)&patch[rr * 68 + cp];
      const int gcol = n0 + (cp >> 5) * 128 + wn * 32 + (cp & 31);
      *(float4*)&C[(size_t)(grow0 + rr) * ldc + gcol] = v;
    }
    __builtin_amdgcn_wave_barrier();
  }
}

// ---------------- fused QKV' projection (BM=BN=256, XCD-swizzled) ------------
// tile in [0,384): wsel = (tile%12)>>2, n0 = ((tile%12)&3)*256, m0 = (tile/12)*256
__global__ __launch_bounds__(512, 2)
void gemm_qkv(const unsigned short* __restrict__ xb,
              const unsigned short* __restrict__ wq, const unsigned short* __restrict__ wk,
              const unsigned short* __restrict__ wct,
              unsigned short* __restrict__ Q, unsigned short* __restrict__ Kb,
              unsigned short* __restrict__ VT)
{
  // T1 bijective XCD swizzle: 384 tiles, 384 % 8 == 0 -> chunk of 48 per XCD
  const int lin = blockIdx.x + 12 * blockIdx.y;
  const int tile = (lin & 7) * 48 + (lin >> 3);
  const int xp = tile % 12, yp = tile / 12;
  const int m0 = yp * 256;
  const int wsel = xp >> 2;
  const int n0 = (xp & 3) * 256;
  const unsigned short* W = (wsel == 0) ? wq : (wsel == 1) ? wk : wct;

  __shared__ __align__(16) char smem[131072];
  f32x4 acc[8][4] = {};
  kloop8p(xb + (size_t)m0 * 1024, W + (size_t)n0 * 1024, 1024, 1024, 16, smem, acc);
  __syncthreads();

  const int lane = threadIdx.x & 63, wave = threadIdx.x >> 6;
  const int quad = lane >> 4, l16 = lane & 15;
  const int wm = wave >> 2, wn = wave & 3;
  if (wsel == 2) {
#pragma unroll
    for (int mf = 0; mf < 8; ++mf) {
      const int gr = m0 + (mf >> 2) * 128 + wm * 64 + (mf & 3) * 16 + quad * 4;
      const int b = gr >> 11, s = gr & 2047;
#pragma unroll
      for (int an = 0; an < 4; ++an) {
        const int gc = n0 + (an >> 1) * 128 + wn * 32 + (an & 1) * 16 + l16;
        us4 v;
#pragma unroll
        for (int r = 0; r < 4; ++r) v[r] = f2bf(acc[mf][an][r]);
        *(us4*)(VT + (size_t)b * (1024 * 2048) + (size_t)gc * 2048 + s) = v;
      }
    }
  } else {
    epi_bf16(acc, (wsel == 0) ? Q : Kb, 1024, m0, n0, smem);
  }
}

// ---------------- scores GEMM: C = A @ W^T (BM=BN=256, causal skip) ----------
__global__ __launch_bounds__(512, 2)
void gemm_sc(const unsigned short* __restrict__ A, const unsigned short* __restrict__ W,
             unsigned short* __restrict__ C)
{
  const int m0 = blockIdx.y * 256;
  const int n0 = blockIdx.x * 256;
  if (n0 > m0 + 255) return;
  const int z = blockIdx.z;

  __shared__ __align__(16) char smem[131072];
  f32x4 acc[8][4] = {};
  kloop8p(A + (size_t)z * 2048 * 1024 + (size_t)m0 * 1024,
          W + (size_t)z * 2048 * 1024 + (size_t)n0 * 1024,
          1024, 1024, 16, smem, acc);
  __syncthreads();
  epi_bf16(acc, C + (size_t)z * 2048 * 2048, 2048, m0, n0, smem);
}

// ---------------- PV GEMM: split-K x2, XCD-swizzled, no atomics --------------
// 256 tiles: n(4) x m(8) x zz(8); zz = batch*2 + half. Keff = m0+256, each
// half covers Keff/2 (multiple of 128). h=0 -> direct f32 store to out;
// h=1 -> f32 store to partial. out += partial afterwards (add_partial).
__global__ __launch_bounds__(512, 2)
void gemm_pv(const unsigned short* __restrict__ SP, const unsigned short* __restrict__ VT,
             float* __restrict__ out, float* __restrict__ partial)
{
  const int lin = blockIdx.x + 4 * blockIdx.y + 32 * blockIdx.z;
  const int tile = (lin & 7) * 32 + (lin >> 3);   // bijective, 256 % 8 == 0
  const int n0 = (tile & 3) * 256;
  const int m0 = ((tile >> 2) & 7) * 256;
  const int zz = tile >> 5;
  const int z = zz >> 1, h = zz & 1;
  const int Khalf = (m0 + 256) >> 1;              // multiple of 128
  const int kb = h * Khalf;

  __shared__ __align__(16) char smem[131072];
  f32x4 acc[8][4] = {};
  kloop8p(SP + (size_t)z * 2048 * 2048 + (size_t)m0 * 2048 + kb,
          VT + (size_t)z * 1024 * 2048 + (size_t)n0 * 2048 + kb,
          2048, 2048, Khalf >> 6, smem, acc);
  __syncthreads();
  float* C = (h ? partial : out) + (size_t)z * 2048 * 1024;
  epi_f32(acc, C, 1024, m0, n0, smem);
}

// out += partial, 8.4M floats as float4, exact cover
__global__ __launch_bounds__(256)
void add_partial(float* __restrict__ out, const float* __restrict__ partial)
{
  const size_t i = (size_t)blockIdx.x * 256 + threadIdx.x;
  float4 a = ((const float4*)out)[i];
  const float4 b = ((const float4*)partial)[i];
  a.x += b.x; a.y += b.y; a.z += b.z; a.w += b.w;
  ((float4*)out)[i] = a;
}

// ---------------- small 128x128 GEMM (4 waves, BK=32) for Wct ----------------
__global__ __launch_bounds__(256, 4)
void gemm_small(const unsigned short* __restrict__ A, const unsigned short* __restrict__ W,
                unsigned short* __restrict__ C)
{
  const int m0 = blockIdx.y * 128;
  const int n0 = blockIdx.x * 128;
  const int tid = threadIdx.x;
  const int lane = tid & 63, wave = tid >> 6;
  const int quad = lane >> 4, l16 = lane & 15;
  const int wm = wave & 1, wn = wave >> 1;

  __shared__ __align__(16) char smem[16384];
  char* ldsA = smem; char* ldsW = smem + 8192;
  const int wrow = tid >> 2;
  const unsigned short* Ab = A + (size_t)m0 * 1024 + (tid & 3) * 8;
  const unsigned short* Wb = W + (size_t)n0 * 1024 + (tid & 3) * 8;

  f32x4 acc[4][4] = {};
  for (int k0 = 0; k0 < 1024; k0 += 32) {
    __syncthreads();
    GL2LDS(Ab + (size_t)wrow * 1024 + k0,        ldsA +        tid * 16);
    GL2LDS(Ab + (size_t)(wrow + 64) * 1024 + k0, ldsA + 4096 + tid * 16);
    GL2LDS(Wb + (size_t)wrow * 1024 + k0,        ldsW +        tid * 16);
    GL2LDS(Wb + (size_t)(wrow + 64) * 1024 + k0, ldsW + 4096 + tid * 16);
    __syncthreads();
    bf16x8 af[4], wf[4];
#pragma unroll
    for (int mt = 0; mt < 4; ++mt)
      af[mt] = *(const bf16x8*)(ldsA + ((wm * 64 + mt * 16 + l16) * 32 + quad * 8) * 2);
#pragma unroll
    for (int nt = 0; nt < 4; ++nt)
      wf[nt] = *(const bf16x8*)(ldsW + ((wn * 64 + nt * 16 + l16) * 32 + quad * 8) * 2);
#pragma unroll
    for (int mt = 0; mt < 4; ++mt)
#pragma unroll
      for (int nt = 0; nt < 4; ++nt)
        acc[mt][nt] = __builtin_amdgcn_mfma_f32_16x16x32_bf16(af[mt], wf[nt], acc[mt][nt], 0, 0, 0);
  }

  __syncthreads();
  const int gr0 = m0 + wm * 64;
  const int gc0 = n0 + wn * 64;
  unsigned short* patch = (unsigned short*)smem + wave * (16 * 72);
#pragma unroll
  for (int mt = 0; mt < 4; ++mt) {
#pragma unroll
    for (int nt = 0; nt < 4; ++nt)
#pragma unroll
      for (int r = 0; r < 4; ++r)
        patch[(quad * 4 + r) * 72 + nt * 16 + l16] = f2bf(acc[mt][nt][r]);
    __builtin_amdgcn_wave_barrier();
#pragma unroll
    for (int j = 0; j < 2; ++j) {
      const int rr = j * 8 + (lane >> 3);
      us8 v = *(const us8*)&patch[rr * 72 + (lane & 7) * 8];
      *(us8*)&C[(size_t)(gr0 + mt * 16 + rr) * 1024 + gc0 + (lane & 7) * 8] = v;
    }
    __builtin_amdgcn_wave_barrier();
  }
}

// causal softmax; blockIdx.x = b*2048 + r; valid cols [0,r]; scale 1/32 pre-exp.
// Zero-fills out to the 256-aligned band [0, ((r>>8)+1)*256) that BM=256 PV reads.
__global__ __launch_bounds__(256)
void softmax_causal(unsigned short* __restrict__ SP)
{
  const int gid = blockIdx.x;
  const int r   = gid & 2047;
  const int tid = threadIdx.x;
  unsigned short* row = SP + (size_t)gid * 2048;
  const int n  = r + 1;
  const int it = (r >> 8) + 1;   // active 256-col chunks

  float vals[8];
  float lmax = -1e30f;
#pragma unroll
  for (int i = 0; i < 8; ++i) {
    const int c = tid + i * 256;
    if (i < it) {
      const float f = bf2f(row[c]);
      vals[i] = f;
      if (c < n) lmax = fmaxf(lmax, f);
    }
  }
#pragma unroll
  for (int m = 32; m; m >>= 1) lmax = fmaxf(lmax, __shfl_xor(lmax, m, 64));
  __shared__ float redm[4], reds[4];
  if ((tid & 63) == 0) redm[tid >> 6] = lmax;
  __syncthreads();
  lmax = fmaxf(fmaxf(redm[0], redm[1]), fmaxf(redm[2], redm[3]));

  float e[8];
  float lsum = 0.f;
#pragma unroll
  for (int i = 0; i < 8; ++i) {
    const int c = tid + i * 256;
    const float ev = (c < n) ? __expf((vals[i] - lmax) * 0.03125f) : 0.f;
    e[i] = ev;
    lsum += ev;
  }
#pragma unroll
  for (int m = 32; m; m >>= 1) lsum += __shfl_xor(lsum, m, 64);
  if ((tid & 63) == 0) reds[tid >> 6] = lsum;
  __syncthreads();
  lsum = reds[0] + reds[1] + reds[2] + reds[3];
  const float inv = 1.f / lsum;
#pragma unroll
  for (int i = 0; i < 8; ++i) {
    const int c = tid + i * 256;
    if (i < it) row[c] = f2bf(e[i] * inv);
  }
}

extern "C" void kernel_launch(void* const* d_in, const int* in_sizes, int n_in,
                              void* d_out, int out_size, void* d_ws, size_t ws_size,
                              hipStream_t stream)
{
  (void)in_sizes; (void)n_in; (void)out_size; (void)ws_size;
  // dict order: k, q, v, out_proj, x — f32 inputs, f32 output
  const float* wk_f = (const float*)d_in[0];
  const float* wq_f = (const float*)d_in[1];
  const float* wv_f = (const float*)d_in[2];
  const float* wo_f = (const float*)d_in[3];
  const float* x_f  = (const float*)d_in[4];
  float* out = (float*)d_out;

  // ws layout (98 MiB):
  char* p = (char*)d_ws;
  unsigned short* xb   = (unsigned short*)(p);                       // [0,16M)
  unsigned short* Q    = (unsigned short*)(p + ((size_t)16 << 20));  // [16,32M)
  unsigned short* Kb   = (unsigned short*)(p + ((size_t)32 << 20));  // [32,48M)
  unsigned short* VT   = (unsigned short*)(p + ((size_t)48 << 20));  // [48,64M): V'^T [B][j][s]
  unsigned short* SP   = (unsigned short*)(p + ((size_t)64 << 20));  // [64,96M): [B][S][S]
  unsigned short* wqb  = (unsigned short*)(p + ((size_t)64 << 20));  // aliases (dead before scores)
  unsigned short* wkb  = (unsigned short*)(p + ((size_t)66 << 20));
  unsigned short* vtb  = (unsigned short*)(p + ((size_t)68 << 20));  // v^T bf16
  unsigned short* wctb = (unsigned short*)(p + ((size_t)70 << 20));  // Wct = (v^T@out_proj)^T
  unsigned short* opT  = (unsigned short*)(p + ((size_t)96 << 20));  // [96,98M)
  float* partial = (float*)p;   // [0,34M): PV h=1 partial (xb/Q/Kb dead by then)

  dim3 blk256(256), blk512(512);

  // conversions + transposes (x, wq, wk, v^T, out_proj^T)
  prep<<<dim3(12288), blk256, 0, stream>>>(x_f, wq_f, wk_f, wv_f, wo_f, xb, wqb, wkb, vtb, opT);

  // Wct[j][e] = sum_d out_proj[d][j] * v[d][e], tiny GEMM (1024^3) on light tiles
  gemm_small<<<dim3(8, 8), blk256, 0, stream>>>(opT, vtb, wctb);

  // fused Q/K/V' projections: M=8192, N=3*1024, K=1024 (384 blocks, XCD-swizzled)
  gemm_qkv<<<dim3(12, 32), blk512, 0, stream>>>(xb, wqb, wkb, wctb, Q, Kb, VT);

  // scores (all batches): [B][2048,2048] = Q @ K^T, causal block skip (144 live)
  gemm_sc<<<dim3(8, 8, 4), blk512, 0, stream>>>(Q, Kb, SP);

  // P = causal_softmax(scores/32), in place, all batches (256-aligned zero band)
  softmax_causal<<<dim3(8192), blk256, 0, stream>>>(SP);

  // out = P @ V': split-K x2, 256 blocks exactly 1 round, max NT=16
  gemm_pv<<<dim3(4, 8, 8), blk512, 0, stream>>>(SP, VT, out, partial);

  // out += partial (h=1 contributions)
  add_partial<<<dim3(8192), blk256, 0, stream>>>(out, partial);
}

// Round 6
// 269.430 us; speedup vs baseline: 1.0881x; 1.0267x over previous
//
#include <hip/hip_runtime.h>
#include <stdint.h>

typedef __attribute__((ext_vector_type(8))) short bf16x8;   // 8 bf16 = 4 VGPR (MFMA A/B frag)
typedef __attribute__((ext_vector_type(4))) float f32x4;    // MFMA C/D frag
typedef __attribute__((ext_vector_type(4))) unsigned short us4;
typedef __attribute__((ext_vector_type(8))) unsigned short us8;

__device__ __forceinline__ unsigned short f2bf(float f) {   // RNE f32 -> bf16
  union { float f; unsigned u; } x; x.f = f;
  unsigned r = x.u + 0x7FFFu + ((x.u >> 16) & 1u);
  return (unsigned short)(r >> 16);
}
__device__ __forceinline__ float bf2f(unsigned short h) {
  union { unsigned u; float f; } x; x.u = ((unsigned)h) << 16;
  return x.f;
}

// async global->LDS, 16B per lane; LDS dest is wave-uniform base + lane*16
#define GL2LDS(g, l) __builtin_amdgcn_global_load_lds( \
    (const __attribute__((address_space(1))) unsigned int*)(g), \
    (__attribute__((address_space(3))) unsigned int*)(l), 16, 0, 0)

// raw barrier with compiler memory fence (no vmcnt/lgkm drain at runtime)
#define BARRIER() do { asm volatile("" ::: "memory"); \
  __builtin_amdgcn_s_barrier(); asm volatile("" ::: "memory"); } while (0)
#define SCHED0() __builtin_amdgcn_sched_barrier(0)

// ---------------- fused prep (unchanged) ----------------
__global__ __launch_bounds__(256)
void prep(const float* __restrict__ x,
          const float* __restrict__ wq, const float* __restrict__ wk,
          const float* __restrict__ wv, const float* __restrict__ wo,
          unsigned short* __restrict__ xb,
          unsigned short* __restrict__ wqb, unsigned short* __restrict__ wkb,
          unsigned short* __restrict__ vtb, unsigned short* __restrict__ opT)
{
  __shared__ float t[32][33];
  const int b = blockIdx.x;
  if (b < 10240) {
    const float* in; unsigned short* out; int i;
    if (b < 8192)      { in = x;  out = xb;  i = b * 256 + threadIdx.x; }
    else if (b < 9216) { in = wq; out = wqb; i = (b - 8192) * 256 + threadIdx.x; }
    else               { in = wk; out = wkb; i = (b - 9216) * 256 + threadIdx.x; }
    const float4 f = ((const float4*)in)[i];
    us4 v;
    v[0] = f2bf(f.x); v[1] = f2bf(f.y); v[2] = f2bf(f.z); v[3] = f2bf(f.w);
    ((us4*)out)[i] = v;
  } else {
    const float* in = (b < 11264) ? wv : wo;
    unsigned short* out = (b < 11264) ? vtb : opT;
    const int tb = (b < 11264) ? (b - 10240) : (b - 11264);
    const int bx = (tb & 31) * 32, by = (tb >> 5) * 32;
    const int tx = threadIdx.x & 31, ty = threadIdx.x >> 5;
#pragma unroll
    for (int i = 0; i < 32; i += 8)
      t[ty + i][tx] = in[(size_t)(by + ty + i) * 1024 + bx + tx];
    __syncthreads();
#pragma unroll
    for (int i = 0; i < 32; i += 8)
      out[(size_t)(bx + ty + i) * 1024 + by + tx] = f2bf(t[tx][ty + i]);
  }
}

// ======== m201-faithful 256x256 8-phase K-loop (BK=64, 512 thr / 8 waves) ====
// (unchanged — ~950 TF in-block measured at K=1024)
__device__ __forceinline__ void kloop8p(
    const unsigned short* __restrict__ Ag, const unsigned short* __restrict__ Bg,
    const int lda, const int ldw, const int NT,   // NT = K/64, even, >= 2
    char* smem, f32x4 (&acc)[8][4])
{
  const int tid = threadIdx.x;
  const int lane = tid & 63, wave = tid >> 6;
  const int quad = lane >> 4, l16 = lane & 15;
  const int wm = wave >> 2, wn = wave & 3;

  const int c0 = (quad * 16) ^ ((l16 & 7) << 4);   // swizzled ks=0 byte col
  const int aR = (wm * 64 + l16) * 128;            // byte row base in A-half
  const int bR = (wn * 32 + l16) * 128;            // byte row base in B-half

  const int scol = ((tid & 7) ^ ((tid >> 3) & 7)) << 3;   // inv-swizzled elem col
  const unsigned short* As = Ag + (size_t)(tid >> 3) * lda + scol;
  const unsigned short* Bs = Bg + (size_t)(tid >> 3) * ldw + scol;

#define SA(buf, mh, kt) do { \
    GL2LDS(As + (size_t)((mh) * 128) * lda + (kt) * 64,      smem + (buf) * 65536 + (mh) * 16384 +        tid * 16); \
    GL2LDS(As + (size_t)((mh) * 128 + 64) * lda + (kt) * 64, smem + (buf) * 65536 + (mh) * 16384 + 8192 + tid * 16); } while (0)
#define SB(buf, nh, kt) do { \
    GL2LDS(Bs + (size_t)((nh) * 128) * ldw + (kt) * 64,      smem + (buf) * 65536 + 32768 + (nh) * 16384 +        tid * 16); \
    GL2LDS(Bs + (size_t)((nh) * 128 + 64) * ldw + (kt) * 64, smem + (buf) * 65536 + 32768 + (nh) * 16384 + 8192 + tid * 16); } while (0)
#define RA(buf, mh) do { _Pragma("unroll") for (int fi = 0; fi < 4; ++fi) { \
    afr[fi][0] = *(const bf16x8*)(smem + (buf) * 65536 + (mh) * 16384 + aR + fi * 2048 + c0); \
    afr[fi][1] = *(const bf16x8*)(smem + (buf) * 65536 + (mh) * 16384 + aR + fi * 2048 + (c0 ^ 64)); } } while (0)
#define RB(buf, nh, bb) do { _Pragma("unroll") for (int fj = 0; fj < 2; ++fj) { \
    bb[fj][0] = *(const bf16x8*)(smem + (buf) * 65536 + 32768 + (nh) * 16384 + bR + fj * 2048 + c0); \
    bb[fj][1] = *(const bf16x8*)(smem + (buf) * 65536 + 32768 + (nh) * 16384 + bR + fj * 2048 + (c0 ^ 64)); } } while (0)
#define MM(mh, nh, bb) do { __builtin_amdgcn_s_setprio(1); \
    _Pragma("unroll") for (int fi = 0; fi < 4; ++fi) \
    _Pragma("unroll") for (int fj = 0; fj < 2; ++fj) \
    _Pragma("unroll") for (int ks = 0; ks < 2; ++ks) \
      acc[(mh) * 4 + fi][(nh) * 2 + fj] = __builtin_amdgcn_mfma_f32_16x16x32_bf16( \
          afr[fi][ks], bb[fj][ks], acc[(mh) * 4 + fi][(nh) * 2 + fj], 0, 0, 0); \
    __builtin_amdgcn_s_setprio(0); } while (0)

  bf16x8 afr[4][2], b0[2][2], b1[2][2];

  // prologue: tile0 full (8 loads) + tile1 {Ah0, Bh1} (4 loads)
  SA(0, 0, 0); SA(0, 1, 0); SB(0, 0, 0); SB(0, 1, 0);
  SA(1, 0, 1); SB(1, 1, 1);
  asm volatile("s_waitcnt vmcnt(4)" ::: "memory");
  __builtin_amdgcn_s_barrier();

  for (int t = 0; t < NT; t += 2) {
    const bool s2 = (t + 2 < NT), s3 = (t + 3 < NT);

    // ---- p1: tile t, quadrant (0,0)
    RA(0, 0); RB(0, 0, b0);
    SA(1, 1, t + 1);
    BARRIER(); SCHED0(); MM(0, 0, b0); SCHED0(); BARRIER();
    // ---- p2: (0,1)
    RB(0, 1, b1);
    SB(1, 0, t + 1);
    BARRIER(); SCHED0(); MM(0, 1, b1); SCHED0(); BARRIER();
    // ---- p3: (1,1)
    RA(0, 1);
    if (s2) SA(0, 0, t + 2);
    BARRIER(); SCHED0(); MM(1, 1, b1); SCHED0(); BARRIER();
    // ---- p4: (1,0) + gate
    if (s2) SB(0, 1, t + 2);
    BARRIER(); SCHED0(); MM(1, 0, b0);
    if (s2) { asm volatile("s_waitcnt vmcnt(4)" ::: "memory"); }
    else    { asm volatile("s_waitcnt vmcnt(0)" ::: "memory"); }
    SCHED0(); BARRIER();

    // ---- p5: tile t+1, quadrant (0,0)
    RA(1, 0); RB(1, 0, b0);
    if (s2) SA(0, 1, t + 2);
    BARRIER(); SCHED0(); MM(0, 0, b0); SCHED0(); BARRIER();
    // ---- p6: (0,1)
    RB(1, 1, b1);
    if (s2) SB(0, 0, t + 2);
    BARRIER(); SCHED0(); MM(0, 1, b1); SCHED0(); BARRIER();
    // ---- p7: (1,1)
    RA(1, 1);
    if (s3) SA(1, 0, t + 3);
    BARRIER(); SCHED0(); MM(1, 1, b1); SCHED0(); BARRIER();
    // ---- p8: (1,0) + gate
    if (s3) SB(1, 1, t + 3);
    BARRIER(); SCHED0(); MM(1, 0, b0);
    if (s3) { asm volatile("s_waitcnt vmcnt(4)" ::: "memory"); }
    else    { asm volatile("s_waitcnt vmcnt(0)" ::: "memory"); }
    SCHED0(); BARRIER();
  }
#undef SA
#undef SB
#undef RA
#undef RB
#undef MM
}

// ---------------- epilogues (2M x 4N 256^2 layout) ----------------
__device__ __forceinline__ void epi_bf16(const f32x4 (&acc)[8][4], unsigned short* __restrict__ C,
                                         int ldc, int m0, int n0, char* smem)
{
  const int tid = threadIdx.x, lane = tid & 63, wave = tid >> 6;
  const int quad = lane >> 4, l16 = lane & 15;
  const int wm = wave >> 2, wn = wave & 3;
  unsigned short* patch = (unsigned short*)smem + wave * (16 * 72);
#pragma unroll
  for (int mf = 0; mf < 8; ++mf) {
#pragma unroll
    for (int an = 0; an < 4; ++an)
#pragma unroll
      for (int r = 0; r < 4; ++r)
        patch[(quad * 4 + r) * 72 + an * 16 + l16] = f2bf(acc[mf][an][r]);
    __builtin_amdgcn_wave_barrier();
    const int grow0 = m0 + (mf >> 2) * 128 + wm * 64 + (mf & 3) * 16;
#pragma unroll
    for (int it = 0; it < 2; ++it) {
      const int rr = it * 8 + (lane >> 3);
      const int cp = (lane & 7) * 8;
      us8 v = *(const us8*)&patch[rr * 72 + cp];
      const int gcol = n0 + (cp >> 5) * 128 + wn * 32 + (cp & 31);
      *(us8*)&C[(size_t)(grow0 + rr) * ldc + gcol] = v;
    }
    __builtin_amdgcn_wave_barrier();
  }
}

__device__ __forceinline__ void epi_f32(const f32x4 (&acc)[8][4], float* __restrict__ C,
                                        int ldc, int m0, int n0, char* smem)
{
  const int tid = threadIdx.x, lane = tid & 63, wave = tid >> 6;
  const int quad = lane >> 4, l16 = lane & 15;
  const int wm = wave >> 2, wn = wave & 3;
  float* patch = (float*)smem + wave * (16 * 68);
#pragma unroll
  for (int mf = 0; mf < 8; ++mf) {
#pragma unroll
    for (int an = 0; an < 4; ++an)
#pragma unroll
      for (int r = 0; r < 4; ++r)
        patch[(quad * 4 + r) * 68 + an * 16 + l16] = acc[mf][an][r];
    __builtin_amdgcn_wave_barrier();
    const int grow0 = m0 + (mf >> 2) * 128 + wm * 64 + (mf & 3) * 16;
#pragma unroll
    for (int j = 0; j < 4; ++j) {
      const int rr = j * 4 + (lane >> 4);
      const int cp = (lane & 15) * 4;
      float4 v = *(const float4*)&patch[rr * 68 + cp];
      const int gcol = n0 + (cp >> 5) * 128 + wn * 32 + (cp & 31);
      *(float4*)&C[(size_t)(grow0 + rr) * ldc + gcol] = v;
    }
    __builtin_amdgcn_wave_barrier();
  }
}

// ---------------- mega: Wct + Q/K/V' in one launch (400 blocks) --------------
// bid 0-15:    Wct tiles (4x4 of 256^2): C = opT @ vtb^T -> wctb; then
//              release-increment ctr (device scope).
// bid 16-271:  Q/K tiles (256, XCD-swizzled): wsel = sw>>7 (0:Q,1:K).
// bid 272-399: V' tiles (128): acquire-spin until ctr==16 (safe: 128 spinners
//              < 256 CUs -> wct+QK always have CUs to run on; no deadlock),
//              then V' = xb @ wctb^T stored transposed into VT[b][j][s].
__global__ __launch_bounds__(512, 2)
void mega_qkv(const unsigned short* __restrict__ xb,
              const unsigned short* __restrict__ wqb, const unsigned short* __restrict__ wkb,
              const unsigned short* __restrict__ opT, const unsigned short* __restrict__ vtb,
              unsigned short* __restrict__ wctb,
              unsigned short* __restrict__ Q, unsigned short* __restrict__ Kb,
              unsigned short* __restrict__ VT, unsigned* __restrict__ ctr)
{
  const int bid = blockIdx.x;
  __shared__ __align__(16) char smem[131072];
  f32x4 acc[8][4] = {};

  if (bid < 16) {
    // ---- Wct tile
    const int m0 = (bid >> 2) * 256, n0 = (bid & 3) * 256;
    kloop8p(opT + (size_t)m0 * 1024, vtb + (size_t)n0 * 1024, 1024, 1024, 16, smem, acc);
    __syncthreads();
    epi_bf16(acc, wctb, 1024, m0, n0, smem);
    __syncthreads();   // emits vmcnt(0) drain: all waves' stores retired
    if (threadIdx.x == 0) {
      __threadfence();
      __hip_atomic_fetch_add(ctr, 1u, __ATOMIC_RELEASE, __HIP_MEMORY_SCOPE_AGENT);
    }
  } else if (bid < 272) {
    // ---- Q/K tile
    const int idx = bid - 16;
    const int sw = (idx & 7) * 32 + (idx >> 3);       // bijective XCD swizzle
    const int wsel = sw >> 7;                          // 0:Q 1:K
    const int t = sw & 127;
    const int m0 = (t >> 2) * 256, n0 = (t & 3) * 256;
    const unsigned short* W = wsel ? wkb : wqb;
    kloop8p(xb + (size_t)m0 * 1024, W + (size_t)n0 * 1024, 1024, 1024, 16, smem, acc);
    __syncthreads();
    epi_bf16(acc, wsel ? Kb : Q, 1024, m0, n0, smem);
  } else {
    // ---- V' tile (needs wctb)
    while (__hip_atomic_load(ctr, __ATOMIC_ACQUIRE, __HIP_MEMORY_SCOPE_AGENT) < 16u)
      __builtin_amdgcn_s_sleep(8);
    const int idx = bid - 272;
    const int m0 = (idx >> 2) * 256, n0 = (idx & 3) * 256;
    kloop8p(xb + (size_t)m0 * 1024, wctb + (size_t)n0 * 1024, 1024, 1024, 16, smem, acc);
    __syncthreads();
    const int lane = threadIdx.x & 63, wave = threadIdx.x >> 6;
    const int quad = lane >> 4, l16 = lane & 15;
    const int wm = wave >> 2, wn = wave & 3;
#pragma unroll
    for (int mf = 0; mf < 8; ++mf) {
      const int gr = m0 + (mf >> 2) * 128 + wm * 64 + (mf & 3) * 16 + quad * 4;
      const int b = gr >> 11, s = gr & 2047;
#pragma unroll
      for (int an = 0; an < 4; ++an) {
        const int gc = n0 + (an >> 1) * 128 + wn * 32 + (an & 1) * 16 + l16;
        us4 v;
#pragma unroll
        for (int r = 0; r < 4; ++r) v[r] = f2bf(acc[mf][an][r]);
        *(us4*)(VT + (size_t)b * (1024 * 2048) + (size_t)gc * 2048 + s) = v;
      }
    }
  }
}

// ---------------- scores GEMM: C = Q @ K^T (BM=BN=256, causal skip) ----------
__global__ __launch_bounds__(512, 2)
void gemm_sc(const unsigned short* __restrict__ A, const unsigned short* __restrict__ W,
             unsigned short* __restrict__ C)
{
  const int m0 = blockIdx.y * 256;
  const int n0 = blockIdx.x * 256;
  if (n0 > m0 + 255) return;
  const int z = blockIdx.z;

  __shared__ __align__(16) char smem[131072];
  f32x4 acc[8][4] = {};
  kloop8p(A + (size_t)z * 2048 * 1024 + (size_t)m0 * 1024,
          W + (size_t)z * 2048 * 1024 + (size_t)n0 * 1024,
          1024, 1024, 16, smem, acc);
  __syncthreads();
  epi_bf16(acc, C + (size_t)z * 2048 * 2048, 2048, m0, n0, smem);
}

// ---------------- PV GEMM: selective split-K (m0>=1024 only) -----------------
// grid (4, 12, 4): y<4 -> m0i=y unsplit (NT=4,8,12,16); y>=4 -> m0i=4+((y-4)>>1),
// h=(y-4)&1, Khalf=(m0+256)/2 (NT=10,12,14,16). h==1 writes f32 partial at
// rows (m0-1024) of partial[z][1024][1024]; everything else direct to out.
__global__ __launch_bounds__(512, 2)
void gemm_pv(const unsigned short* __restrict__ SP, const unsigned short* __restrict__ VT,
             float* __restrict__ out, float* __restrict__ partial)
{
  const int n0 = blockIdx.x * 256;
  const int y  = blockIdx.y;
  const int z  = blockIdx.z;
  int m0i, h;
  if (y < 4) { m0i = y; h = -1; }
  else       { m0i = 4 + ((y - 4) >> 1); h = (y - 4) & 1; }
  const int m0 = m0i * 256;
  int kb, NT;
  if (h < 0) { kb = 0; NT = (m0 + 256) >> 6; }
  else { const int Kh = (m0 + 256) >> 1; kb = h * Kh; NT = Kh >> 6; }

  __shared__ __align__(16) char smem[131072];
  f32x4 acc[8][4] = {};
  kloop8p(SP + (size_t)z * 2048 * 2048 + (size_t)m0 * 2048 + kb,
          VT + (size_t)z * 1024 * 2048 + (size_t)n0 * 2048 + kb,
          2048, 2048, NT, smem, acc);
  __syncthreads();

  if (h == 1)
    epi_f32(acc, partial + (size_t)z * 1024 * 1024, 1024, m0 - 1024, n0, smem);
  else
    epi_f32(acc, out + (size_t)z * 2048 * 1024, 1024, m0, n0, smem);
}

// out rows [1024,2048) of each batch += partial; 4M f32 = 1M float4, exact
__global__ __launch_bounds__(256)
void add_partial(float* __restrict__ out, const float* __restrict__ partial)
{
  const size_t i = (size_t)blockIdx.x * 256 + threadIdx.x;   // float4 index, < 1M
  const size_t z = i >> 18;                                  // 256K float4 per batch
  const size_t oi = i + (z + 1) * 262144;                    // + (z+1)*1M floats
  float4 a = ((const float4*)out)[oi];
  const float4 b = ((const float4*)partial)[i];
  a.x += b.x; a.y += b.y; a.z += b.z; a.w += b.w;
  ((float4*)out)[oi] = a;
}

// causal softmax; blockIdx.x = b*2048 + r; valid cols [0,r]; scale 1/32 pre-exp.
// Zero-fills out to the 256-aligned band [0, ((r>>8)+1)*256) that BM=256 PV reads.
__global__ __launch_bounds__(256)
void softmax_causal(unsigned short* __restrict__ SP)
{
  const int gid = blockIdx.x;
  const int r   = gid & 2047;
  const int tid = threadIdx.x;
  unsigned short* row = SP + (size_t)gid * 2048;
  const int n  = r + 1;
  const int it = (r >> 8) + 1;   // active 256-col chunks

  float vals[8];
  float lmax = -1e30f;
#pragma unroll
  for (int i = 0; i < 8; ++i) {
    const int c = tid + i * 256;
    if (i < it) {
      const float f = bf2f(row[c]);
      vals[i] = f;
      if (c < n) lmax = fmaxf(lmax, f);
    }
  }
#pragma unroll
  for (int m = 32; m; m >>= 1) lmax = fmaxf(lmax, __shfl_xor(lmax, m, 64));
  __shared__ float redm[4], reds[4];
  if ((tid & 63) == 0) redm[tid >> 6] = lmax;
  __syncthreads();
  lmax = fmaxf(fmaxf(redm[0], redm[1]), fmaxf(redm[2], redm[3]));

  float e[8];
  float lsum = 0.f;
#pragma unroll
  for (int i = 0; i < 8; ++i) {
    const int c = tid + i * 256;
    const float ev = (c < n) ? __expf((vals[i] - lmax) * 0.03125f) : 0.f;
    e[i] = ev;
    lsum += ev;
  }
#pragma unroll
  for (int m = 32; m; m >>= 1) lsum += __shfl_xor(lsum, m, 64);
  if ((tid & 63) == 0) reds[tid >> 6] = lsum;
  __syncthreads();
  lsum = reds[0] + reds[1] + reds[2] + reds[3];
  const float inv = 1.f / lsum;
#pragma unroll
  for (int i = 0; i < 8; ++i) {
    const int c = tid + i * 256;
    if (i < it) row[c] = f2bf(e[i] * inv);
  }
}

extern "C" void kernel_launch(void* const* d_in, const int* in_sizes, int n_in,
                              void* d_out, int out_size, void* d_ws, size_t ws_size,
                              hipStream_t stream)
{
  (void)in_sizes; (void)n_in; (void)out_size; (void)ws_size;
  // dict order: k, q, v, out_proj, x — f32 inputs, f32 output
  const float* wk_f = (const float*)d_in[0];
  const float* wq_f = (const float*)d_in[1];
  const float* wv_f = (const float*)d_in[2];
  const float* wo_f = (const float*)d_in[3];
  const float* x_f  = (const float*)d_in[4];
  float* out = (float*)d_out;

  // ws layout (98 MiB):
  char* p = (char*)d_ws;
  unsigned short* xb   = (unsigned short*)(p);                       // [0,16M)
  unsigned short* Q    = (unsigned short*)(p + ((size_t)16 << 20));  // [16,32M)
  unsigned short* Kb   = (unsigned short*)(p + ((size_t)32 << 20));  // [32,48M)
  unsigned short* VT   = (unsigned short*)(p + ((size_t)48 << 20));  // [48,64M): V'^T [B][j][s]
  unsigned short* SP   = (unsigned short*)(p + ((size_t)64 << 20));  // [64,96M): [B][S][S]
  unsigned short* wqb  = (unsigned short*)(p + ((size_t)64 << 20));  // aliases (dead before scores)
  unsigned short* wkb  = (unsigned short*)(p + ((size_t)66 << 20));
  unsigned short* vtb  = (unsigned short*)(p + ((size_t)68 << 20));  // v^T bf16
  unsigned short* wctb = (unsigned short*)(p + ((size_t)70 << 20));  // Wct = (v^T@out_proj)^T
  unsigned short* opT  = (unsigned short*)(p + ((size_t)96 << 20));  // [96,98M)
  unsigned* ctr  = (unsigned*)(p + ((size_t)80 << 20));              // flag (SP region, dead)
  float* partial = (float*)p;   // [0,16M): PV h=1 partial (xb dead by then)

  dim3 blk256(256), blk512(512);

  // zero the wct-done flag (re-zeroed every graph replay)
  hipMemsetAsync(ctr, 0, 4, stream);

  // conversions + transposes (x, wq, wk, v^T, out_proj^T)
  prep<<<dim3(12288), blk256, 0, stream>>>(x_f, wq_f, wk_f, wv_f, wo_f, xb, wqb, wkb, vtb, opT);

  // Wct + Q/K/V' fused: 400 blocks (16 wct -> flag; 256 Q/K; 128 V' spin on flag)
  mega_qkv<<<dim3(400), blk512, 0, stream>>>(xb, wqb, wkb, opT, vtb, wctb, Q, Kb, VT, ctr);

  // scores (all batches): [B][2048,2048] = Q @ K^T, causal block skip (144 live)
  gemm_sc<<<dim3(8, 8, 4), blk512, 0, stream>>>(Q, Kb, SP);

  // P = causal_softmax(scores/32), in place, all batches (256-aligned zero band)
  softmax_causal<<<dim3(8192), blk256, 0, stream>>>(SP);

  // out = P @ V': selective split-K (m0>=1024), 192 blocks, max NT=16
  gemm_pv<<<dim3(4, 12, 4), blk512, 0, stream>>>(SP, VT, out, partial);

  // out rows [1024,2048) per batch += partial
  add_partial<<<dim3(4096), blk256, 0, stream>>>(out, partial);
}

// Round 7
// 263.699 us; speedup vs baseline: 1.1117x; 1.0217x over previous
//
#include <hip/hip_runtime.h>
#include <stdint.h>

typedef __attribute__((ext_vector_type(8))) short bf16x8;   // 8 bf16 = 4 VGPR (MFMA A/B frag)
typedef __attribute__((ext_vector_type(4))) float f32x4;    // MFMA C/D frag
typedef __attribute__((ext_vector_type(4))) unsigned short us4;
typedef __attribute__((ext_vector_type(8))) unsigned short us8;

__device__ __forceinline__ unsigned short f2bf(float f) {   // RNE f32 -> bf16
  union { float f; unsigned u; } x; x.f = f;
  unsigned r = x.u + 0x7FFFu + ((x.u >> 16) & 1u);
  return (unsigned short)(r >> 16);
}
__device__ __forceinline__ float bf2f(unsigned short h) {
  union { unsigned u; float f; } x; x.u = ((unsigned)h) << 16;
  return x.f;
}

// async global->LDS, 16B per lane; LDS dest is wave-uniform base + lane*16
#define GL2LDS(g, l) __builtin_amdgcn_global_load_lds( \
    (const __attribute__((address_space(1))) unsigned int*)(g), \
    (__attribute__((address_space(3))) unsigned int*)(l), 16, 0, 0)

// raw barrier with compiler memory fence (no vmcnt/lgkm drain at runtime)
#define BARRIER() do { asm volatile("" ::: "memory"); \
  __builtin_amdgcn_s_barrier(); asm volatile("" ::: "memory"); } while (0)
#define SCHED0() __builtin_amdgcn_sched_barrier(0)

// ---------------- fused prep (unchanged) ----------------
__global__ __launch_bounds__(256)
void prep(const float* __restrict__ x,
          const float* __restrict__ wq, const float* __restrict__ wk,
          const float* __restrict__ wv, const float* __restrict__ wo,
          unsigned short* __restrict__ xb,
          unsigned short* __restrict__ wqb, unsigned short* __restrict__ wkb,
          unsigned short* __restrict__ vtb, unsigned short* __restrict__ opT)
{
  __shared__ float t[32][33];
  const int b = blockIdx.x;
  if (b < 10240) {
    const float* in; unsigned short* out; int i;
    if (b < 8192)      { in = x;  out = xb;  i = b * 256 + threadIdx.x; }
    else if (b < 9216) { in = wq; out = wqb; i = (b - 8192) * 256 + threadIdx.x; }
    else               { in = wk; out = wkb; i = (b - 9216) * 256 + threadIdx.x; }
    const float4 f = ((const float4*)in)[i];
    us4 v;
    v[0] = f2bf(f.x); v[1] = f2bf(f.y); v[2] = f2bf(f.z); v[3] = f2bf(f.w);
    ((us4*)out)[i] = v;
  } else {
    const float* in = (b < 11264) ? wv : wo;
    unsigned short* out = (b < 11264) ? vtb : opT;
    const int tb = (b < 11264) ? (b - 10240) : (b - 11264);
    const int bx = (tb & 31) * 32, by = (tb >> 5) * 32;
    const int tx = threadIdx.x & 31, ty = threadIdx.x >> 5;
#pragma unroll
    for (int i = 0; i < 32; i += 8)
      t[ty + i][tx] = in[(size_t)(by + ty + i) * 1024 + bx + tx];
    __syncthreads();
#pragma unroll
    for (int i = 0; i < 32; i += 8)
      out[(size_t)(bx + ty + i) * 1024 + by + tx] = f2bf(t[tx][ty + i]);
  }
}

// ======== m201-faithful 256x256 8-phase K-loop (BK=64, 512 thr / 8 waves) ====
// (unchanged — ~950 TF in-block measured at K=1024)
__device__ __forceinline__ void kloop8p(
    const unsigned short* __restrict__ Ag, const unsigned short* __restrict__ Bg,
    const int lda, const int ldw, const int NT,   // NT = K/64, even, >= 2
    char* smem, f32x4 (&acc)[8][4])
{
  const int tid = threadIdx.x;
  const int lane = tid & 63, wave = tid >> 6;
  const int quad = lane >> 4, l16 = lane & 15;
  const int wm = wave >> 2, wn = wave & 3;

  const int c0 = (quad * 16) ^ ((l16 & 7) << 4);   // swizzled ks=0 byte col
  const int aR = (wm * 64 + l16) * 128;            // byte row base in A-half
  const int bR = (wn * 32 + l16) * 128;            // byte row base in B-half

  const int scol = ((tid & 7) ^ ((tid >> 3) & 7)) << 3;   // inv-swizzled elem col
  const unsigned short* As = Ag + (size_t)(tid >> 3) * lda + scol;
  const unsigned short* Bs = Bg + (size_t)(tid >> 3) * ldw + scol;

#define SA(buf, mh, kt) do { \
    GL2LDS(As + (size_t)((mh) * 128) * lda + (kt) * 64,      smem + (buf) * 65536 + (mh) * 16384 +        tid * 16); \
    GL2LDS(As + (size_t)((mh) * 128 + 64) * lda + (kt) * 64, smem + (buf) * 65536 + (mh) * 16384 + 8192 + tid * 16); } while (0)
#define SB(buf, nh, kt) do { \
    GL2LDS(Bs + (size_t)((nh) * 128) * ldw + (kt) * 64,      smem + (buf) * 65536 + 32768 + (nh) * 16384 +        tid * 16); \
    GL2LDS(Bs + (size_t)((nh) * 128 + 64) * ldw + (kt) * 64, smem + (buf) * 65536 + 32768 + (nh) * 16384 + 8192 + tid * 16); } while (0)
#define RA(buf, mh) do { _Pragma("unroll") for (int fi = 0; fi < 4; ++fi) { \
    afr[fi][0] = *(const bf16x8*)(smem + (buf) * 65536 + (mh) * 16384 + aR + fi * 2048 + c0); \
    afr[fi][1] = *(const bf16x8*)(smem + (buf) * 65536 + (mh) * 16384 + aR + fi * 2048 + (c0 ^ 64)); } } while (0)
#define RB(buf, nh, bb) do { _Pragma("unroll") for (int fj = 0; fj < 2; ++fj) { \
    bb[fj][0] = *(const bf16x8*)(smem + (buf) * 65536 + 32768 + (nh) * 16384 + bR + fj * 2048 + c0); \
    bb[fj][1] = *(const bf16x8*)(smem + (buf) * 65536 + 32768 + (nh) * 16384 + bR + fj * 2048 + (c0 ^ 64)); } } while (0)
#define MM(mh, nh, bb) do { __builtin_amdgcn_s_setprio(1); \
    _Pragma("unroll") for (int fi = 0; fi < 4; ++fi) \
    _Pragma("unroll") for (int fj = 0; fj < 2; ++fj) \
    _Pragma("unroll") for (int ks = 0; ks < 2; ++ks) \
      acc[(mh) * 4 + fi][(nh) * 2 + fj] = __builtin_amdgcn_mfma_f32_16x16x32_bf16( \
          afr[fi][ks], bb[fj][ks], acc[(mh) * 4 + fi][(nh) * 2 + fj], 0, 0, 0); \
    __builtin_amdgcn_s_setprio(0); } while (0)

  bf16x8 afr[4][2], b0[2][2], b1[2][2];

  // prologue: tile0 full (8 loads) + tile1 {Ah0, Bh1} (4 loads)
  SA(0, 0, 0); SA(0, 1, 0); SB(0, 0, 0); SB(0, 1, 0);
  SA(1, 0, 1); SB(1, 1, 1);
  asm volatile("s_waitcnt vmcnt(4)" ::: "memory");
  __builtin_amdgcn_s_barrier();

  for (int t = 0; t < NT; t += 2) {
    const bool s2 = (t + 2 < NT), s3 = (t + 3 < NT);

    // ---- p1: tile t, quadrant (0,0)
    RA(0, 0); RB(0, 0, b0);
    SA(1, 1, t + 1);
    BARRIER(); SCHED0(); MM(0, 0, b0); SCHED0(); BARRIER();
    // ---- p2: (0,1)
    RB(0, 1, b1);
    SB(1, 0, t + 1);
    BARRIER(); SCHED0(); MM(0, 1, b1); SCHED0(); BARRIER();
    // ---- p3: (1,1)
    RA(0, 1);
    if (s2) SA(0, 0, t + 2);
    BARRIER(); SCHED0(); MM(1, 1, b1); SCHED0(); BARRIER();
    // ---- p4: (1,0) + gate
    if (s2) SB(0, 1, t + 2);
    BARRIER(); SCHED0(); MM(1, 0, b0);
    if (s2) { asm volatile("s_waitcnt vmcnt(4)" ::: "memory"); }
    else    { asm volatile("s_waitcnt vmcnt(0)" ::: "memory"); }
    SCHED0(); BARRIER();

    // ---- p5: tile t+1, quadrant (0,0)
    RA(1, 0); RB(1, 0, b0);
    if (s2) SA(0, 1, t + 2);
    BARRIER(); SCHED0(); MM(0, 0, b0); SCHED0(); BARRIER();
    // ---- p6: (0,1)
    RB(1, 1, b1);
    if (s2) SB(0, 0, t + 2);
    BARRIER(); SCHED0(); MM(0, 1, b1); SCHED0(); BARRIER();
    // ---- p7: (1,1)
    RA(1, 1);
    if (s3) SA(1, 0, t + 3);
    BARRIER(); SCHED0(); MM(1, 1, b1); SCHED0(); BARRIER();
    // ---- p8: (1,0) + gate
    if (s3) SB(1, 1, t + 3);
    BARRIER(); SCHED0(); MM(1, 0, b0);
    if (s3) { asm volatile("s_waitcnt vmcnt(4)" ::: "memory"); }
    else    { asm volatile("s_waitcnt vmcnt(0)" ::: "memory"); }
    SCHED0(); BARRIER();
  }
#undef SA
#undef SB
#undef RA
#undef RB
#undef MM
}

// ---------------- epilogues (2M x 4N 256^2 layout) ----------------
__device__ __forceinline__ void epi_bf16(const f32x4 (&acc)[8][4], unsigned short* __restrict__ C,
                                         int ldc, int m0, int n0, char* smem)
{
  const int tid = threadIdx.x, lane = tid & 63, wave = tid >> 6;
  const int quad = lane >> 4, l16 = lane & 15;
  const int wm = wave >> 2, wn = wave & 3;
  unsigned short* patch = (unsigned short*)smem + wave * (16 * 72);
#pragma unroll
  for (int mf = 0; mf < 8; ++mf) {
#pragma unroll
    for (int an = 0; an < 4; ++an)
#pragma unroll
      for (int r = 0; r < 4; ++r)
        patch[(quad * 4 + r) * 72 + an * 16 + l16] = f2bf(acc[mf][an][r]);
    __builtin_amdgcn_wave_barrier();
    const int grow0 = m0 + (mf >> 2) * 128 + wm * 64 + (mf & 3) * 16;
#pragma unroll
    for (int it = 0; it < 2; ++it) {
      const int rr = it * 8 + (lane >> 3);
      const int cp = (lane & 7) * 8;
      us8 v = *(const us8*)&patch[rr * 72 + cp];
      const int gcol = n0 + (cp >> 5) * 128 + wn * 32 + (cp & 31);
      *(us8*)&C[(size_t)(grow0 + rr) * ldc + gcol] = v;
    }
    __builtin_amdgcn_wave_barrier();
  }
}

__device__ __forceinline__ void epi_f32(const f32x4 (&acc)[8][4], float* __restrict__ C,
                                        int ldc, int m0, int n0, char* smem)
{
  const int tid = threadIdx.x, lane = tid & 63, wave = tid >> 6;
  const int quad = lane >> 4, l16 = lane & 15;
  const int wm = wave >> 2, wn = wave & 3;
  float* patch = (float*)smem + wave * (16 * 68);
#pragma unroll
  for (int mf = 0; mf < 8; ++mf) {
#pragma unroll
    for (int an = 0; an < 4; ++an)
#pragma unroll
      for (int r = 0; r < 4; ++r)
        patch[(quad * 4 + r) * 68 + an * 16 + l16] = acc[mf][an][r];
    __builtin_amdgcn_wave_barrier();
    const int grow0 = m0 + (mf >> 2) * 128 + wm * 64 + (mf & 3) * 16;
#pragma unroll
    for (int j = 0; j < 4; ++j) {
      const int rr = j * 4 + (lane >> 4);
      const int cp = (lane & 15) * 4;
      float4 v = *(const float4*)&patch[rr * 68 + cp];
      const int gcol = n0 + (cp >> 5) * 128 + wn * 32 + (cp & 31);
      *(float4*)&C[(size_t)(grow0 + rr) * ldc + gcol] = v;
    }
    __builtin_amdgcn_wave_barrier();
  }
}

// ---------------- mega helpers ----------------
__device__ __forceinline__ void do_qk(int idx, const unsigned short* __restrict__ xb,
    const unsigned short* __restrict__ wqb, const unsigned short* __restrict__ wkb,
    unsigned short* __restrict__ Q, unsigned short* __restrict__ Kb, char* smem)
{
  const int sw = (idx & 7) * 32 + (idx >> 3);   // bijective XCD swizzle over 256
  const int wsel = sw >> 7;                     // 0:Q 1:K
  const int t = sw & 127;
  const int m0 = (t >> 2) * 256, n0 = (t & 3) * 256;
  f32x4 acc[8][4] = {};
  kloop8p(xb + (size_t)m0 * 1024, (wsel ? wkb : wqb) + (size_t)n0 * 1024,
          1024, 1024, 16, smem, acc);
  __syncthreads();
  epi_bf16(acc, wsel ? Kb : Q, 1024, m0, n0, smem);
}

__device__ __forceinline__ void do_vp(int idx, const unsigned short* __restrict__ xb,
    const unsigned short* __restrict__ wctb, unsigned short* __restrict__ VT, char* smem)
{
  const int m0 = (idx >> 2) * 256, n0 = (idx & 3) * 256;
  f32x4 acc[8][4] = {};
  kloop8p(xb + (size_t)m0 * 1024, wctb + (size_t)n0 * 1024, 1024, 1024, 16, smem, acc);
  __syncthreads();
  const int lane = threadIdx.x & 63, wave = threadIdx.x >> 6;
  const int quad = lane >> 4, l16 = lane & 15;
  const int wm = wave >> 2, wn = wave & 3;
#pragma unroll
  for (int mf = 0; mf < 8; ++mf) {
    const int gr = m0 + (mf >> 2) * 128 + wm * 64 + (mf & 3) * 16 + quad * 4;
    const int b = gr >> 11, s = gr & 2047;
#pragma unroll
    for (int an = 0; an < 4; ++an) {
      const int gc = n0 + (an >> 1) * 128 + wn * 32 + (an & 1) * 16 + l16;
      us4 v;
#pragma unroll
      for (int r = 0; r < 4; ++r) v[r] = f2bf(acc[mf][an][r]);
      *(us4*)(VT + (size_t)b * (1024 * 2048) + (size_t)gc * 2048 + s) = v;
    }
  }
}

// ---------------- mega: persistent 2-slot, 256 blocks (all resident) --------
// slot1: bid 0-15 wct (4x4 of 256^2, then release ctr); bid 16-255 QK idx 0-239.
// slot2: bid 0-15 QK idx 240-255; bid 16-143 V' idx 0-127 (acquire-spin ctr==16,
// safe: all 256 blocks resident at 1 block/CU -> producers always running).
__global__ __launch_bounds__(512, 2)
void mega_qkv(const unsigned short* __restrict__ xb,
              const unsigned short* __restrict__ wqb, const unsigned short* __restrict__ wkb,
              const unsigned short* __restrict__ opT, const unsigned short* __restrict__ vtb,
              unsigned short* __restrict__ wctb,
              unsigned short* __restrict__ Q, unsigned short* __restrict__ Kb,
              unsigned short* __restrict__ VT, unsigned* __restrict__ ctr)
{
  const int bid = blockIdx.x;
  __shared__ __align__(16) char smem[131072];

  // ---- slot 1
  if (bid < 16) {
    const int m0 = (bid >> 2) * 256, n0 = (bid & 3) * 256;
    f32x4 acc[8][4] = {};
    kloop8p(opT + (size_t)m0 * 1024, vtb + (size_t)n0 * 1024, 1024, 1024, 16, smem, acc);
    __syncthreads();
    epi_bf16(acc, wctb, 1024, m0, n0, smem);
    __syncthreads();   // all waves' stores issued & drained (vmcnt(0) at barrier)
    if (threadIdx.x == 0) {
      __threadfence();
      __hip_atomic_fetch_add(ctr, 1u, __ATOMIC_RELEASE, __HIP_MEMORY_SCOPE_AGENT);
    }
  } else {
    do_qk(bid - 16, xb, wqb, wkb, Q, Kb, smem);
  }

  __syncthreads();   // protect smem reuse between slots

  // ---- slot 2
  if (bid < 16) {
    do_qk(240 + bid, xb, wqb, wkb, Q, Kb, smem);
  } else if (bid < 144) {
    while (__hip_atomic_load(ctr, __ATOMIC_ACQUIRE, __HIP_MEMORY_SCOPE_AGENT) < 16u)
      __builtin_amdgcn_s_sleep(8);
    do_vp(bid - 16, xb, wctb, VT, smem);
  }
}

// ---------------- scores GEMM: C = Q @ K^T (BM=BN=256, causal skip) ----------
__global__ __launch_bounds__(512, 2)
void gemm_sc(const unsigned short* __restrict__ A, const unsigned short* __restrict__ W,
             unsigned short* __restrict__ C)
{
  const int m0 = blockIdx.y * 256;
  const int n0 = blockIdx.x * 256;
  if (n0 > m0 + 255) return;
  const int z = blockIdx.z;

  __shared__ __align__(16) char smem[131072];
  f32x4 acc[8][4] = {};
  kloop8p(A + (size_t)z * 2048 * 1024 + (size_t)m0 * 1024,
          W + (size_t)z * 2048 * 1024 + (size_t)n0 * 1024,
          1024, 1024, 16, smem, acc);
  __syncthreads();
  epi_bf16(acc, C + (size_t)z * 2048 * 2048, 2048, m0, n0, smem);
}

// ---------------- PV GEMM: selective split-K (m0>=1024 only) -----------------
// grid (4, 12, 4): y<4 -> m0i=y unsplit (NT=4,8,12,16); y>=4 -> m0i=4+((y-4)>>1),
// h=(y-4)&1, Khalf=(m0+256)/2 (NT=10,12,14,16). h==1 writes f32 partial at
// rows (m0-1024) of partial[z][1024][1024]; everything else direct to out.
__global__ __launch_bounds__(512, 2)
void gemm_pv(const unsigned short* __restrict__ SP, const unsigned short* __restrict__ VT,
             float* __restrict__ out, float* __restrict__ partial)
{
  const int n0 = blockIdx.x * 256;
  const int y  = blockIdx.y;
  const int z  = blockIdx.z;
  int m0i, h;
  if (y < 4) { m0i = y; h = -1; }
  else       { m0i = 4 + ((y - 4) >> 1); h = (y - 4) & 1; }
  const int m0 = m0i * 256;
  int kb, NT;
  if (h < 0) { kb = 0; NT = (m0 + 256) >> 6; }
  else { const int Kh = (m0 + 256) >> 1; kb = h * Kh; NT = Kh >> 6; }

  __shared__ __align__(16) char smem[131072];
  f32x4 acc[8][4] = {};
  kloop8p(SP + (size_t)z * 2048 * 2048 + (size_t)m0 * 2048 + kb,
          VT + (size_t)z * 1024 * 2048 + (size_t)n0 * 2048 + kb,
          2048, 2048, NT, smem, acc);
  __syncthreads();

  if (h == 1)
    epi_f32(acc, partial + (size_t)z * 1024 * 1024, 1024, m0 - 1024, n0, smem);
  else
    epi_f32(acc, out + (size_t)z * 2048 * 1024, 1024, m0, n0, smem);
}

// out rows [1024,2048) of each batch += partial; 4M f32 = 1M float4, exact
__global__ __launch_bounds__(256)
void add_partial(float* __restrict__ out, const float* __restrict__ partial)
{
  const size_t i = (size_t)blockIdx.x * 256 + threadIdx.x;   // float4 index, < 1M
  const size_t z = i >> 18;                                  // 256K float4 per batch
  const size_t oi = i + (z + 1) * 262144;                    // + (z+1)*1M floats
  float4 a = ((const float4*)out)[oi];
  const float4 b = ((const float4*)partial)[i];
  a.x += b.x; a.y += b.y; a.z += b.z; a.w += b.w;
  ((float4*)out)[oi] = a;
}

// causal softmax; blockIdx.x = b*2048 + r; valid cols [0,r]; scale 1/32 pre-exp.
// Vectorized us8: thread tid owns cols [tid*8, tid*8+8). Zero-fills out to the
// 256-aligned band [0, ((r>>8)+1)*256) that BM=256 PV reads.
__global__ __launch_bounds__(256)
void softmax_causal(unsigned short* __restrict__ SP)
{
  const int gid = blockIdx.x;
  const int r   = gid & 2047;
  const int tid = threadIdx.x;
  unsigned short* row = SP + (size_t)gid * 2048;
  const int n    = r + 1;
  const int nact = ((r >> 8) + 1) << 5;   // active threads (8 cols each)
  const int c0   = tid * 8;
  const bool act = tid < nact;

  float v[8];
  float lmax = -1e30f;
  if (act) {
    const us8 pk = ((const us8*)row)[tid];
#pragma unroll
    for (int j = 0; j < 8; ++j) {
      v[j] = bf2f(pk[j]);
      if (c0 + j < n) lmax = fmaxf(lmax, v[j]);
    }
  }
#pragma unroll
  for (int m = 32; m; m >>= 1) lmax = fmaxf(lmax, __shfl_xor(lmax, m, 64));
  __shared__ float redm[4], reds[4];
  if ((tid & 63) == 0) redm[tid >> 6] = lmax;
  __syncthreads();
  lmax = fmaxf(fmaxf(redm[0], redm[1]), fmaxf(redm[2], redm[3]));

  float e[8];
  float lsum = 0.f;
  if (act) {
#pragma unroll
    for (int j = 0; j < 8; ++j) {
      const float ev = (c0 + j < n) ? __expf((v[j] - lmax) * 0.03125f) : 0.f;
      e[j] = ev;
      lsum += ev;
    }
  }
#pragma unroll
  for (int m = 32; m; m >>= 1) lsum += __shfl_xor(lsum, m, 64);
  if ((tid & 63) == 0) reds[tid >> 6] = lsum;
  __syncthreads();
  lsum = reds[0] + reds[1] + reds[2] + reds[3];
  const float inv = 1.f / lsum;
  if (act) {
    us8 o;
#pragma unroll
    for (int j = 0; j < 8; ++j) o[j] = f2bf(e[j] * inv);
    ((us8*)row)[tid] = o;
  }
}

extern "C" void kernel_launch(void* const* d_in, const int* in_sizes, int n_in,
                              void* d_out, int out_size, void* d_ws, size_t ws_size,
                              hipStream_t stream)
{
  (void)in_sizes; (void)n_in; (void)out_size; (void)ws_size;
  // dict order: k, q, v, out_proj, x — f32 inputs, f32 output
  const float* wk_f = (const float*)d_in[0];
  const float* wq_f = (const float*)d_in[1];
  const float* wv_f = (const float*)d_in[2];
  const float* wo_f = (const float*)d_in[3];
  const float* x_f  = (const float*)d_in[4];
  float* out = (float*)d_out;

  // ws layout (98 MiB):
  char* p = (char*)d_ws;
  unsigned short* xb   = (unsigned short*)(p);                       // [0,16M)
  unsigned short* Q    = (unsigned short*)(p + ((size_t)16 << 20));  // [16,32M)
  unsigned short* Kb   = (unsigned short*)(p + ((size_t)32 << 20));  // [32,48M)
  unsigned short* VT   = (unsigned short*)(p + ((size_t)48 << 20));  // [48,64M): V'^T [B][j][s]
  unsigned short* SP   = (unsigned short*)(p + ((size_t)64 << 20));  // [64,96M): [B][S][S]
  unsigned short* wqb  = (unsigned short*)(p + ((size_t)64 << 20));  // aliases (dead before scores)
  unsigned short* wkb  = (unsigned short*)(p + ((size_t)66 << 20));
  unsigned short* vtb  = (unsigned short*)(p + ((size_t)68 << 20));  // v^T bf16
  unsigned short* wctb = (unsigned short*)(p + ((size_t)70 << 20));  // Wct = (v^T@out_proj)^T
  unsigned short* opT  = (unsigned short*)(p + ((size_t)96 << 20));  // [96,98M)
  unsigned* ctr  = (unsigned*)(p + ((size_t)80 << 20));              // flag (SP region, dead)
  float* partial = (float*)p;   // [0,16M): PV h=1 partial (xb dead by then)

  dim3 blk256(256), blk512(512);

  // zero the wct-done flag (re-zeroed every graph replay)
  hipMemsetAsync(ctr, 0, 4, stream);

  // conversions + transposes (x, wq, wk, v^T, out_proj^T)
  prep<<<dim3(12288), blk256, 0, stream>>>(x_f, wq_f, wk_f, wv_f, wo_f, xb, wqb, wkb, vtb, opT);

  // Wct + Q/K/V' fused: persistent 2-slot, 256 blocks (all resident)
  mega_qkv<<<dim3(256), blk512, 0, stream>>>(xb, wqb, wkb, opT, vtb, wctb, Q, Kb, VT, ctr);

  // scores (all batches): [B][2048,2048] = Q @ K^T, causal block skip (144 live)
  gemm_sc<<<dim3(8, 8, 4), blk512, 0, stream>>>(Q, Kb, SP);

  // P = causal_softmax(scores/32), in place, all batches (256-aligned zero band)
  softmax_causal<<<dim3(8192), blk256, 0, stream>>>(SP);

  // out = P @ V': selective split-K (m0>=1024), 192 blocks, max NT=16
  gemm_pv<<<dim3(4, 12, 4), blk512, 0, stream>>>(SP, VT, out, partial);

  // out rows [1024,2048) per batch += partial
  add_partial<<<dim3(4096), blk256, 0, stream>>>(out, partial);
}

// Round 9
// 262.388 us; speedup vs baseline: 1.1173x; 1.0050x over previous
//
#include <hip/hip_runtime.h>
#include <stdint.h>

typedef __attribute__((ext_vector_type(8))) short bf16x8;   // 8 bf16 = 4 VGPR (MFMA A/B frag)
typedef __attribute__((ext_vector_type(4))) float f32x4;    // MFMA C/D frag
typedef __attribute__((ext_vector_type(4))) unsigned short us4;
typedef __attribute__((ext_vector_type(8))) unsigned short us8;

__device__ __forceinline__ unsigned short f2bf(float f) {   // RNE f32 -> bf16
  union { float f; unsigned u; } x; x.f = f;
  unsigned r = x.u + 0x7FFFu + ((x.u >> 16) & 1u);
  return (unsigned short)(r >> 16);
}
__device__ __forceinline__ float bf2f(unsigned short h) {
  union { unsigned u; float f; } x; x.u = ((unsigned)h) << 16;
  return x.f;
}

// async global->LDS, 16B per lane; LDS dest is wave-uniform base + lane*16
#define GL2LDS(g, l) __builtin_amdgcn_global_load_lds( \
    (const __attribute__((address_space(1))) unsigned int*)(g), \
    (__attribute__((address_space(3))) unsigned int*)(l), 16, 0, 0)

// raw barrier with compiler memory fence (no vmcnt/lgkm drain at runtime)
#define BARRIER() do { asm volatile("" ::: "memory"); \
  __builtin_amdgcn_s_barrier(); asm volatile("" ::: "memory"); } while (0)
#define SCHED0() __builtin_amdgcn_sched_barrier(0)

// ---------------- fused prep (unchanged) ----------------
__global__ __launch_bounds__(256)
void prep(const float* __restrict__ x,
          const float* __restrict__ wq, const float* __restrict__ wk,
          const float* __restrict__ wv, const float* __restrict__ wo,
          unsigned short* __restrict__ xb,
          unsigned short* __restrict__ wqb, unsigned short* __restrict__ wkb,
          unsigned short* __restrict__ vtb, unsigned short* __restrict__ opT)
{
  __shared__ float t[32][33];
  const int b = blockIdx.x;
  if (b < 10240) {
    const float* in; unsigned short* out; int i;
    if (b < 8192)      { in = x;  out = xb;  i = b * 256 + threadIdx.x; }
    else if (b < 9216) { in = wq; out = wqb; i = (b - 8192) * 256 + threadIdx.x; }
    else               { in = wk; out = wkb; i = (b - 9216) * 256 + threadIdx.x; }
    const float4 f = ((const float4*)in)[i];
    us4 v;
    v[0] = f2bf(f.x); v[1] = f2bf(f.y); v[2] = f2bf(f.z); v[3] = f2bf(f.w);
    ((us4*)out)[i] = v;
  } else {
    const float* in = (b < 11264) ? wv : wo;
    unsigned short* out = (b < 11264) ? vtb : opT;
    const int tb = (b < 11264) ? (b - 10240) : (b - 11264);
    const int bx = (tb & 31) * 32, by = (tb >> 5) * 32;
    const int tx = threadIdx.x & 31, ty = threadIdx.x >> 5;
#pragma unroll
    for (int i = 0; i < 32; i += 8)
      t[ty + i][tx] = in[(size_t)(by + ty + i) * 1024 + bx + tx];
    __syncthreads();
#pragma unroll
    for (int i = 0; i < 32; i += 8)
      out[(size_t)(bx + ty + i) * 1024 + by + tx] = f2bf(t[tx][ty + i]);
  }
}

// ======== m201-faithful 256x256 8-phase K-loop (BK=64, 512 thr / 8 waves) ====
// (unchanged — ~950 TF in-block measured at K=1024)
__device__ __forceinline__ void kloop8p(
    const unsigned short* __restrict__ Ag, const unsigned short* __restrict__ Bg,
    const int lda, const int ldw, const int NT,   // NT = K/64, even, >= 2
    char* smem, f32x4 (&acc)[8][4])
{
  const int tid = threadIdx.x;
  const int lane = tid & 63, wave = tid >> 6;
  const int quad = lane >> 4, l16 = lane & 15;
  const int wm = wave >> 2, wn = wave & 3;

  const int c0 = (quad * 16) ^ ((l16 & 7) << 4);   // swizzled ks=0 byte col
  const int aR = (wm * 64 + l16) * 128;            // byte row base in A-half
  const int bR = (wn * 32 + l16) * 128;            // byte row base in B-half

  const int scol = ((tid & 7) ^ ((tid >> 3) & 7)) << 3;   // inv-swizzled elem col
  const unsigned short* As = Ag + (size_t)(tid >> 3) * lda + scol;
  const unsigned short* Bs = Bg + (size_t)(tid >> 3) * ldw + scol;

#define SA(buf, mh, kt) do { \
    GL2LDS(As + (size_t)((mh) * 128) * lda + (kt) * 64,      smem + (buf) * 65536 + (mh) * 16384 +        tid * 16); \
    GL2LDS(As + (size_t)((mh) * 128 + 64) * lda + (kt) * 64, smem + (buf) * 65536 + (mh) * 16384 + 8192 + tid * 16); } while (0)
#define SB(buf, nh, kt) do { \
    GL2LDS(Bs + (size_t)((nh) * 128) * ldw + (kt) * 64,      smem + (buf) * 65536 + 32768 + (nh) * 16384 +        tid * 16); \
    GL2LDS(Bs + (size_t)((nh) * 128 + 64) * ldw + (kt) * 64, smem + (buf) * 65536 + 32768 + (nh) * 16384 + 8192 + tid * 16); } while (0)
#define RA(buf, mh) do { _Pragma("unroll") for (int fi = 0; fi < 4; ++fi) { \
    afr[fi][0] = *(const bf16x8*)(smem + (buf) * 65536 + (mh) * 16384 + aR + fi * 2048 + c0); \
    afr[fi][1] = *(const bf16x8*)(smem + (buf) * 65536 + (mh) * 16384 + aR + fi * 2048 + (c0 ^ 64)); } } while (0)
#define RB(buf, nh, bb) do { _Pragma("unroll") for (int fj = 0; fj < 2; ++fj) { \
    bb[fj][0] = *(const bf16x8*)(smem + (buf) * 65536 + 32768 + (nh) * 16384 + bR + fj * 2048 + c0); \
    bb[fj][1] = *(const bf16x8*)(smem + (buf) * 65536 + 32768 + (nh) * 16384 + bR + fj * 2048 + (c0 ^ 64)); } } while (0)
#define MM(mh, nh, bb) do { __builtin_amdgcn_s_setprio(1); \
    _Pragma("unroll") for (int fi = 0; fi < 4; ++fi) \
    _Pragma("unroll") for (int fj = 0; fj < 2; ++fj) \
    _Pragma("unroll") for (int ks = 0; ks < 2; ++ks) \
      acc[(mh) * 4 + fi][(nh) * 2 + fj] = __builtin_amdgcn_mfma_f32_16x16x32_bf16( \
          afr[fi][ks], bb[fj][ks], acc[(mh) * 4 + fi][(nh) * 2 + fj], 0, 0, 0); \
    __builtin_amdgcn_s_setprio(0); } while (0)

  bf16x8 afr[4][2], b0[2][2], b1[2][2];

  // prologue: tile0 full (8 loads) + tile1 {Ah0, Bh1} (4 loads)
  SA(0, 0, 0); SA(0, 1, 0); SB(0, 0, 0); SB(0, 1, 0);
  SA(1, 0, 1); SB(1, 1, 1);
  asm volatile("s_waitcnt vmcnt(4)" ::: "memory");
  __builtin_amdgcn_s_barrier();

  for (int t = 0; t < NT; t += 2) {
    const bool s2 = (t + 2 < NT), s3 = (t + 3 < NT);

    // ---- p1: tile t, quadrant (0,0)
    RA(0, 0); RB(0, 0, b0);
    SA(1, 1, t + 1);
    BARRIER(); SCHED0(); MM(0, 0, b0); SCHED0(); BARRIER();
    // ---- p2: (0,1)
    RB(0, 1, b1);
    SB(1, 0, t + 1);
    BARRIER(); SCHED0(); MM(0, 1, b1); SCHED0(); BARRIER();
    // ---- p3: (1,1)
    RA(0, 1);
    if (s2) SA(0, 0, t + 2);
    BARRIER(); SCHED0(); MM(1, 1, b1); SCHED0(); BARRIER();
    // ---- p4: (1,0) + gate
    if (s2) SB(0, 1, t + 2);
    BARRIER(); SCHED0(); MM(1, 0, b0);
    if (s2) { asm volatile("s_waitcnt vmcnt(4)" ::: "memory"); }
    else    { asm volatile("s_waitcnt vmcnt(0)" ::: "memory"); }
    SCHED0(); BARRIER();

    // ---- p5: tile t+1, quadrant (0,0)
    RA(1, 0); RB(1, 0, b0);
    if (s2) SA(0, 1, t + 2);
    BARRIER(); SCHED0(); MM(0, 0, b0); SCHED0(); BARRIER();
    // ---- p6: (0,1)
    RB(1, 1, b1);
    if (s2) SB(0, 0, t + 2);
    BARRIER(); SCHED0(); MM(0, 1, b1); SCHED0(); BARRIER();
    // ---- p7: (1,1)
    RA(1, 1);
    if (s3) SA(1, 0, t + 3);
    BARRIER(); SCHED0(); MM(1, 1, b1); SCHED0(); BARRIER();
    // ---- p8: (1,0) + gate
    if (s3) SB(1, 1, t + 3);
    BARRIER(); SCHED0(); MM(1, 0, b0);
    if (s3) { asm volatile("s_waitcnt vmcnt(4)" ::: "memory"); }
    else    { asm volatile("s_waitcnt vmcnt(0)" ::: "memory"); }
    SCHED0(); BARRIER();
  }
#undef SA
#undef SB
#undef RA
#undef RB
#undef MM
}

// ---------------- epilogues (2M x 4N 256^2 layout) ----------------
__device__ __forceinline__ void epi_bf16(const f32x4 (&acc)[8][4], unsigned short* __restrict__ C,
                                         int ldc, int m0, int n0, char* smem)
{
  const int tid = threadIdx.x, lane = tid & 63, wave = tid >> 6;
  const int quad = lane >> 4, l16 = lane & 15;
  const int wm = wave >> 2, wn = wave & 3;
  unsigned short* patch = (unsigned short*)smem + wave * (16 * 72);
#pragma unroll
  for (int mf = 0; mf < 8; ++mf) {
#pragma unroll
    for (int an = 0; an < 4; ++an)
#pragma unroll
      for (int r = 0; r < 4; ++r)
        patch[(quad * 4 + r) * 72 + an * 16 + l16] = f2bf(acc[mf][an][r]);
    __builtin_amdgcn_wave_barrier();
    const int grow0 = m0 + (mf >> 2) * 128 + wm * 64 + (mf & 3) * 16;
#pragma unroll
    for (int it = 0; it < 2; ++it) {
      const int rr = it * 8 + (lane >> 3);
      const int cp = (lane & 7) * 8;
      us8 v = *(const us8*)&patch[rr * 72 + cp];
      const int gcol = n0 + (cp >> 5) * 128 + wn * 32 + (cp & 31);
      *(us8*)&C[(size_t)(grow0 + rr) * ldc + gcol] = v;
    }
    __builtin_amdgcn_wave_barrier();
  }
}

__device__ __forceinline__ void epi_f32(const f32x4 (&acc)[8][4], float* __restrict__ C,
                                        int ldc, int m0, int n0, char* smem)
{
  const int tid = threadIdx.x, lane = tid & 63, wave = tid >> 6;
  const int quad = lane >> 4, l16 = lane & 15;
  const int wm = wave >> 2, wn = wave & 3;
  float* patch = (float*)smem + wave * (16 * 68);
#pragma unroll
  for (int mf = 0; mf < 8; ++mf) {
#pragma unroll
    for (int an = 0; an < 4; ++an)
#pragma unroll
      for (int r = 0; r < 4; ++r)
        patch[(quad * 4 + r) * 68 + an * 16 + l16] = acc[mf][an][r];
    __builtin_amdgcn_wave_barrier();
    const int grow0 = m0 + (mf >> 2) * 128 + wm * 64 + (mf & 3) * 16;
#pragma unroll
    for (int j = 0; j < 4; ++j) {
      const int rr = j * 4 + (lane >> 4);
      const int cp = (lane & 15) * 4;
      float4 v = *(const float4*)&patch[rr * 68 + cp];
      const int gcol = n0 + (cp >> 5) * 128 + wn * 32 + (cp & 31);
      *(float4*)&C[(size_t)(grow0 + rr) * ldc + gcol] = v;
    }
    __builtin_amdgcn_wave_barrier();
  }
}

// ---------------- mega helpers ----------------
__device__ __forceinline__ void do_qk(int idx, const unsigned short* __restrict__ xb,
    const unsigned short* __restrict__ wqb, const unsigned short* __restrict__ wkb,
    unsigned short* __restrict__ Q, unsigned short* __restrict__ Kb, char* smem)
{
  const int sw = (idx & 7) * 32 + (idx >> 3);   // bijective XCD swizzle over 256
  const int wsel = sw >> 7;                     // 0:Q 1:K
  const int t = sw & 127;
  const int m0 = (t >> 2) * 256, n0 = (t & 3) * 256;
  f32x4 acc[8][4] = {};
  kloop8p(xb + (size_t)m0 * 1024, (wsel ? wkb : wqb) + (size_t)n0 * 1024,
          1024, 1024, 16, smem, acc);
  __syncthreads();
  epi_bf16(acc, wsel ? Kb : Q, 1024, m0, n0, smem);
}

// V' tile with LDS-coalesced transposed store: per mf, stage the 32-row x
// 256-col slab into patch[256][38] (stride 19 banks, coprime w/ 32 -> no
// conflicts), then write VT[j][s] as 2 x 16B per thread (col = tid>>1,
// row-group g = tid&1 covering the wm half 0/1 at global offset g*64).
__device__ __forceinline__ void do_vp(int idx, const unsigned short* __restrict__ xb,
    const unsigned short* __restrict__ wctb, unsigned short* __restrict__ VT, char* smem)
{
  const int m0 = (idx >> 2) * 256, n0 = (idx & 3) * 256;
  f32x4 acc[8][4] = {};
  kloop8p(xb + (size_t)m0 * 1024, wctb + (size_t)n0 * 1024, 1024, 1024, 16, smem, acc);
  __syncthreads();
  const int tid = threadIdx.x;
  const int lane = tid & 63, wave = tid >> 6;
  const int quad = lane >> 4, l16 = lane & 15;
  const int wm = wave >> 2, wn = wave & 3;
  unsigned short* patch = (unsigned short*)smem;            // [256][38]
  const int bz = m0 >> 11, sbase = m0 & 2047;               // tile within one batch
  unsigned short* VTb = VT + (size_t)bz * (1024 * 2048);
  const int colw = tid >> 1, g = tid & 1;                   // store-side mapping
#pragma unroll
  for (int mf = 0; mf < 8; ++mf) {
#pragma unroll
    for (int an = 0; an < 4; ++an) {
      const int col = (an >> 1) * 128 + wn * 32 + (an & 1) * 16 + l16;
#pragma unroll
      for (int r = 0; r < 4; ++r)
        patch[col * 38 + wm * 16 + quad * 4 + r] = f2bf(acc[mf][an][r]);
    }
    __syncthreads();
    const int s0 = sbase + (mf >> 2) * 128 + (mf & 3) * 16 + g * 64;
    us8 v0 = *(const us8*)&patch[colw * 38 + g * 16];
    us8 v1 = *(const us8*)&patch[colw * 38 + g * 16 + 8];
    *(us8*)&VTb[(size_t)(n0 + colw) * 2048 + s0]     = v0;
    *(us8*)&VTb[(size_t)(n0 + colw) * 2048 + s0 + 8] = v1;
    __syncthreads();
  }
}

// ---------------- mega: persistent 2-slot, 256 blocks --------
// slot1: bid 0-15 wct (4x4 of 256^2, then release ctr); bid 16-255 QK idx 0-239.
// slot2: bid 0-15 QK idx 240-255; bid 16-143 V' idx 0-127 (acquire-spin ctr==16).
// Deadlock-free by counting: at most 128 spinners; producers (bid<16) do their
// work unconditionally in slot 1, and 240 non-producers < 256 CUs, so wct
// always has CUs to run on regardless of dispatch order (no co-residency
// assumption — unlike a full grid barrier).
__global__ __launch_bounds__(512, 2)
void mega_qkv(const unsigned short* __restrict__ xb,
              const unsigned short* __restrict__ wqb, const unsigned short* __restrict__ wkb,
              const unsigned short* __restrict__ opT, const unsigned short* __restrict__ vtb,
              unsigned short* __restrict__ wctb,
              unsigned short* __restrict__ Q, unsigned short* __restrict__ Kb,
              unsigned short* __restrict__ VT, unsigned* __restrict__ ctr)
{
  const int bid = blockIdx.x;
  __shared__ __align__(16) char smem[131072];

  // ---- slot 1
  if (bid < 16) {
    const int m0 = (bid >> 2) * 256, n0 = (bid & 3) * 256;
    f32x4 acc[8][4] = {};
    kloop8p(opT + (size_t)m0 * 1024, vtb + (size_t)n0 * 1024, 1024, 1024, 16, smem, acc);
    __syncthreads();
    epi_bf16(acc, wctb, 1024, m0, n0, smem);
    __syncthreads();   // all waves' stores issued & drained (vmcnt(0) at barrier)
    if (threadIdx.x == 0) {
      __threadfence();
      __hip_atomic_fetch_add(ctr, 1u, __ATOMIC_RELEASE, __HIP_MEMORY_SCOPE_AGENT);
    }
  } else {
    do_qk(bid - 16, xb, wqb, wkb, Q, Kb, smem);
  }

  __syncthreads();   // protect smem reuse between slots

  // ---- slot 2
  if (bid < 16) {
    do_qk(240 + bid, xb, wqb, wkb, Q, Kb, smem);
  } else if (bid < 144) {
    while (__hip_atomic_load(ctr, __ATOMIC_ACQUIRE, __HIP_MEMORY_SCOPE_AGENT) < 16u)
      __builtin_amdgcn_s_sleep(8);
    do_vp(bid - 16, xb, wctb, VT, smem);
  }
}

// ---------------- scores GEMM: C = Q @ K^T (BM=BN=256, causal skip) ----------
__global__ __launch_bounds__(512, 2)
void gemm_sc(const unsigned short* __restrict__ A, const unsigned short* __restrict__ W,
             unsigned short* __restrict__ C)
{
  const int m0 = blockIdx.y * 256;
  const int n0 = blockIdx.x * 256;
  if (n0 > m0 + 255) return;
  const int z = blockIdx.z;

  __shared__ __align__(16) char smem[131072];
  f32x4 acc[8][4] = {};
  kloop8p(A + (size_t)z * 2048 * 1024 + (size_t)m0 * 1024,
          W + (size_t)z * 2048 * 1024 + (size_t)n0 * 1024,
          1024, 1024, 16, smem, acc);
  __syncthreads();
  epi_bf16(acc, C + (size_t)z * 2048 * 2048, 2048, m0, n0, smem);
}

// ---------------- PV GEMM: selective split-K (m0>=1024 only) -----------------
__global__ __launch_bounds__(512, 2)
void gemm_pv(const unsigned short* __restrict__ SP, const unsigned short* __restrict__ VT,
             float* __restrict__ out, float* __restrict__ partial)
{
  const int n0 = blockIdx.x * 256;
  const int y  = blockIdx.y;
  const int z  = blockIdx.z;
  int m0i, h;
  if (y < 4) { m0i = y; h = -1; }
  else       { m0i = 4 + ((y - 4) >> 1); h = (y - 4) & 1; }
  const int m0 = m0i * 256;
  int kb, NT;
  if (h < 0) { kb = 0; NT = (m0 + 256) >> 6; }
  else { const int Kh = (m0 + 256) >> 1; kb = h * Kh; NT = Kh >> 6; }

  __shared__ __align__(16) char smem[131072];
  f32x4 acc[8][4] = {};
  kloop8p(SP + (size_t)z * 2048 * 2048 + (size_t)m0 * 2048 + kb,
          VT + (size_t)z * 1024 * 2048 + (size_t)n0 * 2048 + kb,
          2048, 2048, NT, smem, acc);
  __syncthreads();

  if (h == 1)
    epi_f32(acc, partial + (size_t)z * 1024 * 1024, 1024, m0 - 1024, n0, smem);
  else
    epi_f32(acc, out + (size_t)z * 2048 * 1024, 1024, m0, n0, smem);
}

// out rows [1024,2048) of each batch += partial; 4M f32 = 1M float4, exact
__global__ __launch_bounds__(256)
void add_partial(float* __restrict__ out, const float* __restrict__ partial)
{
  const size_t i = (size_t)blockIdx.x * 256 + threadIdx.x;   // float4 index, < 1M
  const size_t z = i >> 18;                                  // 256K float4 per batch
  const size_t oi = i + (z + 1) * 262144;                    // + (z+1)*1M floats
  float4 a = ((const float4*)out)[oi];
  const float4 b = ((const float4*)partial)[i];
  a.x += b.x; a.y += b.y; a.z += b.z; a.w += b.w;
  ((float4*)out)[oi] = a;
}

// causal softmax; blockIdx.x = b*2048 + r; valid cols [0,r]; scale 1/32 pre-exp.
// Vectorized us8: thread tid owns cols [tid*8, tid*8+8). Zero-fills out to the
// 256-aligned band [0, ((r>>8)+1)*256) that BM=256 PV reads.
__global__ __launch_bounds__(256)
void softmax_causal(unsigned short* __restrict__ SP)
{
  const int gid = blockIdx.x;
  const int r   = gid & 2047;
  const int tid = threadIdx.x;
  unsigned short* row = SP + (size_t)gid * 2048;
  const int n    = r + 1;
  const int nact = ((r >> 8) + 1) << 5;   // active threads (8 cols each)
  const int c0   = tid * 8;
  const bool act = tid < nact;

  float v[8];
  float lmax = -1e30f;
  if (act) {
    const us8 pk = ((const us8*)row)[tid];
#pragma unroll
    for (int j = 0; j < 8; ++j) {
      v[j] = bf2f(pk[j]);
      if (c0 + j < n) lmax = fmaxf(lmax, v[j]);
    }
  }
#pragma unroll
  for (int m = 32; m; m >>= 1) lmax = fmaxf(lmax, __shfl_xor(lmax, m, 64));
  __shared__ float redm[4], reds[4];
  if ((tid & 63) == 0) redm[tid >> 6] = lmax;
  __syncthreads();
  lmax = fmaxf(fmaxf(redm[0], redm[1]), fmaxf(redm[2], redm[3]));

  float e[8];
  float lsum = 0.f;
  if (act) {
#pragma unroll
    for (int j = 0; j < 8; ++j) {
      const float ev = (c0 + j < n) ? __expf((v[j] - lmax) * 0.03125f) : 0.f;
      e[j] = ev;
      lsum += ev;
    }
  }
#pragma unroll
  for (int m = 32; m; m >>= 1) lsum += __shfl_xor(lsum, m, 64);
  if ((tid & 63) == 0) reds[tid >> 6] = lsum;
  __syncthreads();
  lsum = reds[0] + reds[1] + reds[2] + reds[3];
  const float inv = 1.f / lsum;
  if (act) {
    us8 o;
#pragma unroll
    for (int j = 0; j < 8; ++j) o[j] = f2bf(e[j] * inv);
    ((us8*)row)[tid] = o;
  }
}

extern "C" void kernel_launch(void* const* d_in, const int* in_sizes, int n_in,
                              void* d_out, int out_size, void* d_ws, size_t ws_size,
                              hipStream_t stream)
{
  (void)in_sizes; (void)n_in; (void)out_size; (void)ws_size;
  // dict order: k, q, v, out_proj, x — f32 inputs, f32 output
  const float* wk_f = (const float*)d_in[0];
  const float* wq_f = (const float*)d_in[1];
  const float* wv_f = (const float*)d_in[2];
  const float* wo_f = (const float*)d_in[3];
  const float* x_f  = (const float*)d_in[4];
  float* out = (float*)d_out;

  // ws layout (98 MiB):
  char* p = (char*)d_ws;
  unsigned short* xb   = (unsigned short*)(p);                       // [0,16M)
  unsigned short* Q    = (unsigned short*)(p + ((size_t)16 << 20));  // [16,32M)
  unsigned short* Kb   = (unsigned short*)(p + ((size_t)32 << 20));  // [32,48M)
  unsigned short* VT   = (unsigned short*)(p + ((size_t)48 << 20));  // [48,64M): V'^T [B][j][s]
  unsigned short* SP   = (unsigned short*)(p + ((size_t)64 << 20));  // [64,96M): [B][S][S]
  unsigned short* wqb  = (unsigned short*)(p + ((size_t)64 << 20));  // aliases (dead before scores)
  unsigned short* wkb  = (unsigned short*)(p + ((size_t)66 << 20));
  unsigned short* vtb  = (unsigned short*)(p + ((size_t)68 << 20));  // v^T bf16
  unsigned short* wctb = (unsigned short*)(p + ((size_t)70 << 20));  // Wct = (v^T@out_proj)^T
  unsigned short* opT  = (unsigned short*)(p + ((size_t)96 << 20));  // [96,98M)
  unsigned* ctr  = (unsigned*)(p + ((size_t)80 << 20));              // flag (SP region, dead)
  float* partial = (float*)p;   // [0,16M): PV h=1 partial (xb dead by then)

  dim3 blk256(256), blk512(512);

  // zero the wct-done flag (re-zeroed every graph replay)
  hipMemsetAsync(ctr, 0, 4, stream);

  // conversions + transposes (x, wq, wk, v^T, out_proj^T)
  prep<<<dim3(12288), blk256, 0, stream>>>(x_f, wq_f, wk_f, wv_f, wo_f, xb, wqb, wkb, vtb, opT);

  // Wct + Q/K/V' fused: persistent 2-slot, 256 blocks
  mega_qkv<<<dim3(256), blk512, 0, stream>>>(xb, wqb, wkb, opT, vtb, wctb, Q, Kb, VT, ctr);

  // scores (all batches): [B][2048,2048] = Q @ K^T, causal block skip (144 live)
  gemm_sc<<<dim3(8, 8, 4), blk512, 0, stream>>>(Q, Kb, SP);

  // P = causal_softmax(scores/32), in place, all batches (256-aligned zero band)
  softmax_causal<<<dim3(8192), blk256, 0, stream>>>(SP);

  // out = P @ V': selective split-K (m0>=1024), 192 blocks, max NT=16
  gemm_pv<<<dim3(4, 12, 4), blk512, 0, stream>>>(SP, VT, out, partial);

  // out rows [1024,2048) per batch += partial
  add_partial<<<dim3(4096), blk256, 0, stream>>>(out, partial);
}